// Round 6
// baseline (1417.223 us; speedup 1.0000x reference)
//
#include <hip/hip_runtime.h>
#include <math.h>

// ---- problem constants ----
#define N_NODES 33
#define SEQ 24
#define BATCH 64
#define G_GRAPHS (BATCH * SEQ)          // 1536
#define EPG 64
#define E_EDGES (G_GRAPHS * EPG)        // 98304
#define N_TOTAL (G_GRAPHS * N_NODES)    // 50688
#define HID 64
#define HEADS 8
#define HC (HID * HEADS)                // 512
#define LSTM1_H 128
#define LSTM2_H 64
#define NEG_SLOPE 0.2f

// graph chunking: 6 chunks of 256 graphs keeps peak ws ~77 MB (<96.3 MB known-safe)
#define N_CHUNKS 6
#define CHUNK_G (G_GRAPHS / N_CHUNKS)   // 256 graphs
#define CHUNK_N (CHUNK_G * N_NODES)     // 8448 nodes (264 tiles of 32)

__device__ __forceinline__ float sigmoidf_(float x) { return 1.f / (1.f + expf(-x)); }
__device__ __forceinline__ float eluf_(float x) { return x > 0.f ? x : expm1f(x); }
__device__ __forceinline__ float lreluf_(float x) { return x > 0.f ? x : NEG_SLOPE * x; }

// bf16 (RNE) pack/unpack on raw shorts
__device__ __forceinline__ short f2bf(float x) {
  unsigned u = __float_as_uint(x);
  unsigned r = (u + 0x7fffu + ((u >> 16) & 1u)) >> 16;
  return (short)r;
}
__device__ __forceinline__ float bf2f(short b) {
  return __uint_as_float(((unsigned)(unsigned short)b) << 16);
}

typedef __attribute__((ext_vector_type(8))) short bf16x8;
typedef __attribute__((ext_vector_type(4))) float f32x4;

__device__ __forceinline__ void gl2lds16(const void* g, void* l) {
  __builtin_amdgcn_global_load_lds(
      (__attribute__((address_space(1))) const unsigned int*)g,
      (__attribute__((address_space(3))) unsigned int*)l, 16, 0, 0);
}

// ============================================================
// GAT layer 1 (round-4 version — conflict-free, verified)
// ============================================================
__global__ __launch_bounds__(256) void gat1_kernel(
    const float* __restrict__ x, const int* __restrict__ src, const int* __restrict__ dst,
    const float* __restrict__ ea, const float* __restrict__ Wl, const float* __restrict__ Wr,
    const float* __restrict__ We, const float* __restrict__ att, const float* __restrict__ bias,
    short* __restrict__ h1hi, short* __restrict__ h1lo, int g0) {
  __shared__ alignas(16) float Wl_s[2 * 512];
  __shared__ alignas(16) float Wr_s[2 * 512];
  __shared__ alignas(16) float We_s[3 * 512];
  __shared__ alignas(16) float att_s[512];
  __shared__ float xs0_s[N_NODES + 1], xs1_s[N_NODES + 1];
  __shared__ float easX[EPG], easY[EPG], easZ[EPG];
  __shared__ float logit_s[HEADS * 65];   // padded stride 65
  __shared__ int sloc[EPG], dloc[EPG], deg[N_NODES], start[N_NODES], fill[N_NODES], elist[EPG];

  const int g = g0 + blockIdx.x, tid = threadIdx.x;
  const int nb = g * N_NODES, eb = g * EPG;
  const int lb = blockIdx.x * N_NODES;

  for (int i = tid; i < 1024; i += 256) { Wl_s[i] = Wl[i]; Wr_s[i] = Wr[i]; }
  for (int i = tid; i < 1536; i += 256) We_s[i] = We[i];
  for (int i = tid; i < 512; i += 256) att_s[i] = att[i];
  if (tid < 2 * N_NODES) {
    float v = x[nb * 2 + tid];
    if (tid & 1) xs1_s[tid >> 1] = v; else xs0_s[tid >> 1] = v;
  }
  if (tid < EPG) {
    easX[tid] = ea[(eb + tid) * 3 + 0];
    easY[tid] = ea[(eb + tid) * 3 + 1];
    easZ[tid] = ea[(eb + tid) * 3 + 2];
    sloc[tid] = src[eb + tid] - nb;
    dloc[tid] = dst[eb + tid] - nb;
  }
  if (tid < N_NODES) { deg[tid] = 0; fill[tid] = 0; }
  __syncthreads();
  if (tid < EPG) atomicAdd(&deg[dloc[tid]], 1);
  __syncthreads();
  if (tid == 0) { int a = 0; for (int n = 0; n < N_NODES; ++n) { start[n] = a; a += deg[n]; } }
  __syncthreads();
  if (tid < EPG) { int d = dloc[tid]; int p = atomicAdd(&fill[d], 1); elist[start[d] + p] = tid; }

  // logits: h = t>>6 (wave-uniform), e = t&63 (= lane). Weight reads broadcast.
  for (int t = tid; t < EPG * HEADS; t += 256) {
    int h = t >> 6, e = t & 63;
    int s = sloc[e], d = dloc[e];
    float xs0 = xs0_s[s], xs1 = xs1_s[s], xd0 = xs0_s[d], xd1 = xs1_s[d];
    float e0 = easX[e], e1 = easY[e], e2 = easZ[e];
    float acc = 0.f;
    int base = h * 64;
    #pragma unroll
    for (int c4 = 0; c4 < 16; ++c4) {
      int j = base + c4 * 4;
      f32x4 wl0 = *(const f32x4*)(Wl_s + j);
      f32x4 wl1 = *(const f32x4*)(Wl_s + 512 + j);
      f32x4 wr0 = *(const f32x4*)(Wr_s + j);
      f32x4 wr1 = *(const f32x4*)(Wr_s + 512 + j);
      f32x4 we0 = *(const f32x4*)(We_s + j);
      f32x4 we1 = *(const f32x4*)(We_s + 512 + j);
      f32x4 we2 = *(const f32x4*)(We_s + 1024 + j);
      f32x4 at  = *(const f32x4*)(att_s + j);
      #pragma unroll
      for (int q = 0; q < 4; ++q) {
        float v = xs0 * wl0[q] + xs1 * wl1[q]
                + xd0 * wr0[q] + xd1 * wr1[q]
                + e0 * we0[q] + e1 * we1[q] + e2 * we2[q];
        acc += lreluf_(v) * at[q];
      }
    }
    logit_s[h * 65 + e] = acc;
  }
  __syncthreads();

  // segment softmax: h = t>>6 (uniform), n = t&63 (lane), skip n>=33
  for (int t = tid; t < HEADS * 64; t += 256) {
    int h = t >> 6, n = t & 63;
    if (n < N_NODES) {
      int s0 = start[n], dn = deg[n];
      float mx = -1e30f;
      for (int i = 0; i < dn; ++i) mx = fmaxf(mx, logit_s[h * 65 + elist[s0 + i]]);
      float den = 0.f;
      for (int i = 0; i < dn; ++i) den += expf(logit_s[h * 65 + elist[s0 + i]] - mx);
      float inv = 1.f / (den + 1e-16f);
      for (int i = 0; i < dn; ++i) {
        int e = elist[s0 + i];
        logit_s[h * 65 + e] = expf(logit_s[h * 65 + e] - mx) * inv;
      }
    }
  }
  __syncthreads();

  // aggregation: task = (n, 8-channel block). n = t>>6 wave-uniform, jb = lane.
  for (int t = tid; t < N_NODES * 64; t += 256) {
    int n = t >> 6, jb = t & 63;
    int j0 = jb * 8, h = jb >> 3;
    f32x4 wa0 = *(const f32x4*)(Wl_s + j0);
    f32x4 wa1 = *(const f32x4*)(Wl_s + j0 + 4);
    f32x4 wb0 = *(const f32x4*)(Wl_s + 512 + j0);
    f32x4 wb1 = *(const f32x4*)(Wl_s + 512 + j0 + 4);
    float acc[8] = {};
    int s0 = start[n], dn = deg[n];
    for (int i = 0; i < dn; ++i) {
      int e = elist[s0 + i]; int s = sloc[e];
      float a = logit_s[h * 65 + e];
      float ax0 = a * xs0_s[s], ax1 = a * xs1_s[s];
      #pragma unroll
      for (int q = 0; q < 4; ++q) {
        acc[q]     += ax0 * wa0[q] + ax1 * wb0[q];
        acc[4 + q] += ax0 * wa1[q] + ax1 * wb1[q];
      }
    }
    f32x4 b0 = *(const f32x4*)(bias + j0);
    f32x4 b1 = *(const f32x4*)(bias + j0 + 4);
    bf16x8 vh, vl;
    #pragma unroll
    for (int cc = 0; cc < 8; ++cc) {
      float bb = (cc < 4) ? b0[cc] : b1[cc - 4];
      float v = eluf_(acc[cc] + bb);
      short hb = f2bf(v);
      vh[cc] = hb;
      vl[cc] = f2bf(v - bf2f(hb));
    }
    size_t o = (size_t)(lb + n) * HC + j0;
    *(bf16x8*)(h1hi + o) = vh;
    *(bf16x8*)(h1lo + o) = vl;
  }
}

// ============================================================
// weight conversion kernels (unchanged)
// ============================================================
__global__ __launch_bounds__(256) void conv_g2w(
    const float* __restrict__ Wl, const float* __restrict__ Wr,
    short* __restrict__ Bhi, short* __restrict__ Blo) {
  int idx = blockIdx.x * 256 + threadIdx.x;
  int n = idx >> 9, k = idx & 511;
  float v = (n < 512) ? Wl[k * 512 + n] : Wr[k * 512 + (n - 512)];
  short hi = f2bf(v);
  Bhi[idx] = hi;
  Blo[idx] = f2bf(v - bf2f(hi));
}

__global__ __launch_bounds__(256) void conv_w1(
    const float* __restrict__ W, short* __restrict__ Whi, short* __restrict__ Wlo, int total) {
  int idx = blockIdx.x * 256 + threadIdx.x;
  if (idx >= total) return;
  float v = W[idx];
  short hi = f2bf(v);
  Whi[idx] = hi;
  Wlo[idx] = f2bf(v - bf2f(hi));
}

// ============================================================
// A-stationary barrier-free GEMM, K=512 fixed:
//   C[M,N] = (Ahi+Alo)[M,512] @ (Bhi+Blo)[N,512]^T  (3-term split-bf16)
// Block = 32 A-rows (full K, hi+lo = 64 KB LDS, XOR-swizzled 16B units)
// x 128 B-cols. ONE barrier after staging; K-loop has no syncs: A from
// read-only LDS, B streamed global->VGPR (B tot 2 MB -> L2-resident).
// Waves 2x2: wave row-half (16 rows) x col-half (64 cols = 4 subtiles).
// ============================================================
__global__ __launch_bounds__(256) void gemm_as512(
    const short* __restrict__ Ahi, const short* __restrict__ Alo,
    const short* __restrict__ Bhi, const short* __restrict__ Blo,
    float* __restrict__ C, int M, int N) {
  constexpr int K = 512;
  __shared__ short Ah_s[32 * K];   // 32 KB
  __shared__ short Al_s[32 * K];   // 32 KB
  const int tid = threadIdx.x;
  const int wave = tid >> 6, lane = tid & 63;
  const int wm = wave >> 1, wn = wave & 1;
  const int bm = blockIdx.y * 32, bn = blockIdx.x * 128;

  // stage A slab: one gl2lds16 = one full 1024B row (64 lanes x 16B).
  // XOR swizzle: LDS 16B-unit u of row r holds global unit (u ^ (r&7)).
  #pragma unroll
  for (int i = 0; i < 8; ++i) {
    int r = wave * 8 + i;
    size_t gro = (size_t)(bm + r) * K + ((lane ^ (r & 7)) << 3);
    gl2lds16(Ahi + gro, Ah_s + r * K);
    gl2lds16(Alo + gro, Al_s + r * K);
  }
  __syncthreads();

  const int fr = lane & 15, quad = lane >> 4;
  const int ar = wm * 16 + fr;          // A row this lane reads
  const int asw = ar & 7;               // its swizzle key
  const int acol0 = bn + wn * 64;       // wave's first output col

  f32x4 acc[4];
  #pragma unroll
  for (int st = 0; st < 4; ++st) acc[st] = {0.f, 0.f, 0.f, 0.f};

  const size_t bstride = (size_t)K;     // elems per B row
  const short* bh_base = Bhi + (size_t)(acol0 + fr) * bstride + quad * 8;
  const short* bl_base = Blo + (size_t)(acol0 + fr) * bstride + quad * 8;

  #pragma unroll 2
  for (int k0 = 0; k0 < K; k0 += 32) {
    int unit = (k0 >> 3) + quad;
    int aoff = ar * K + (((unit) ^ asw) << 3);
    bf16x8 a_h = *(const bf16x8*)(Ah_s + aoff);
    bf16x8 a_l = *(const bf16x8*)(Al_s + aoff);
    bf16x8 b_h[4], b_l[4];
    #pragma unroll
    for (int st = 0; st < 4; ++st) {
      b_h[st] = *(const bf16x8*)(bh_base + (size_t)st * 16 * bstride + k0);
      b_l[st] = *(const bf16x8*)(bl_base + (size_t)st * 16 * bstride + k0);
    }
    #pragma unroll
    for (int st = 0; st < 4; ++st) {
      acc[st] = __builtin_amdgcn_mfma_f32_16x16x32_bf16(a_h, b_h[st], acc[st], 0, 0, 0);
      acc[st] = __builtin_amdgcn_mfma_f32_16x16x32_bf16(a_h, b_l[st], acc[st], 0, 0, 0);
      acc[st] = __builtin_amdgcn_mfma_f32_16x16x32_bf16(a_l, b_h[st], acc[st], 0, 0, 0);
    }
  }

  // epilogue: C/D layout col=lane&15, row=quad*4+reg  [m89/m91 verified]
  #pragma unroll
  for (int st = 0; st < 4; ++st) {
    int col = acol0 + st * 16 + fr;
    #pragma unroll
    for (int r = 0; r < 4; ++r) {
      int row = bm + wm * 16 + quad * 4 + r;
      C[(size_t)row * N + col] = acc[st][r];
    }
  }
}

// ============================================================
// split-bf16 MFMA GEMM (barriered BK=32; kept for the K=2112 final GEMM)
// ============================================================
template <int WM, int WN>
__global__ __launch_bounds__(256) void gemm_mfma(
    const short* __restrict__ Ahi, const short* __restrict__ Alo,
    const short* __restrict__ Bhi, const short* __restrict__ Blo,
    float* __restrict__ C, const float* __restrict__ bias1, const float* __restrict__ bias2,
    int M, int N, int K) {
  constexpr int BM = 32 * WM, BN = 32 * WN;
  __shared__ short lds[(BM + BN) * 32 * 2];
  short* Ah_s = lds;
  short* Bh_s = Ah_s + BM * 32;
  short* Al_s = Bh_s + BN * 32;
  short* Bl_s = Al_s + BM * 32;

  const int tid = threadIdx.x;
  const int wave = tid >> 6, lane = tid & 63;
  const int wm = wave >> 1, wn = wave & 1;
  const int bm = blockIdx.y * BM, bn = blockIdx.x * BN;

  const int rA = lane >> 2;
  const int cA = (lane & 3) * 8;

  f32x4 acc[WM][WN];
  #pragma unroll
  for (int tm = 0; tm < WM; ++tm)
    #pragma unroll
    for (int tn = 0; tn < WN; ++tn) acc[tm][tn] = {0.f, 0.f, 0.f, 0.f};

  for (int k0 = 0; k0 < K; k0 += 32) {
    #pragma unroll
    for (int i = 0; i < BM / 64; ++i) {
      int row = i * 64 + wave * 16;
      size_t go = (size_t)(bm + row + rA) * K + k0 + cA;
      int lo = (row)*32;
      gl2lds16(Ahi + go, Ah_s + lo);
      gl2lds16(Alo + go, Al_s + lo);
    }
    #pragma unroll
    for (int i = 0; i < BN / 64; ++i) {
      int row = i * 64 + wave * 16;
      size_t go = (size_t)(bn + row + rA) * K + k0 + cA;
      int lo = (row)*32;
      gl2lds16(Bhi + go, Bh_s + lo);
      gl2lds16(Blo + go, Bl_s + lo);
    }
    __syncthreads();

    bf16x8 a_h[WM], a_l[WM], b_h[WN], b_l[WN];
    const int fr = lane & 15;
    const int fk = (lane >> 4) * 8;
    #pragma unroll
    for (int tm = 0; tm < WM; ++tm) {
      int r = (wm * WM + tm) * 16 + fr;
      a_h[tm] = *(const bf16x8*)(Ah_s + r * 32 + fk);
      a_l[tm] = *(const bf16x8*)(Al_s + r * 32 + fk);
    }
    #pragma unroll
    for (int tn = 0; tn < WN; ++tn) {
      int r = (wn * WN + tn) * 16 + fr;
      b_h[tn] = *(const bf16x8*)(Bh_s + r * 32 + fk);
      b_l[tn] = *(const bf16x8*)(Bl_s + r * 32 + fk);
    }
    #pragma unroll
    for (int tm = 0; tm < WM; ++tm)
      #pragma unroll
      for (int tn = 0; tn < WN; ++tn) {
        acc[tm][tn] = __builtin_amdgcn_mfma_f32_16x16x32_bf16(a_h[tm], b_h[tn], acc[tm][tn], 0, 0, 0);
        acc[tm][tn] = __builtin_amdgcn_mfma_f32_16x16x32_bf16(a_h[tm], b_l[tn], acc[tm][tn], 0, 0, 0);
        acc[tm][tn] = __builtin_amdgcn_mfma_f32_16x16x32_bf16(a_l[tm], b_h[tn], acc[tm][tn], 0, 0, 0);
      }
    __syncthreads();
  }

  const int col0 = lane & 15, rq = (lane >> 4) * 4;
  #pragma unroll
  for (int tm = 0; tm < WM; ++tm)
    #pragma unroll
    for (int tn = 0; tn < WN; ++tn) {
      int col = bn + (wn * WN + tn) * 16 + col0;
      float badd = 0.f;
      if (bias1) badd += bias1[col];
      if (bias2) badd += bias2[col];
      #pragma unroll
      for (int r = 0; r < 4; ++r) {
        int row = bm + (wm * WM + tm) * 16 + rq + r;
        C[(size_t)row * N + col] = acc[tm][tn][r] + badd;
      }
    }
}

// ============================================================
// GAT layer 2 (round-4 version — verified)
// ============================================================
__global__ __launch_bounds__(256) void gat2_kernel(
    const float* __restrict__ xlr, const int* __restrict__ src, const int* __restrict__ dst,
    const float* __restrict__ ea, const float* __restrict__ We,
    const float* __restrict__ att, const float* __restrict__ bias,
    short* __restrict__ h2hi, short* __restrict__ h2lo, int g0) {
  __shared__ float xl_s[512 * N_NODES];   // [j][s]
  __shared__ float xr_s[512 * N_NODES];   // [j][d]
  __shared__ alignas(16) float We_s[3 * 512];
  __shared__ alignas(16) float att_s[512];
  __shared__ float b_s[HID];
  __shared__ float easX[EPG], easY[EPG], easZ[EPG];
  __shared__ float logit_s[HEADS * 65];
  __shared__ int sloc[EPG], dloc[EPG], deg[N_NODES], start[N_NODES], fill[N_NODES], elist[EPG];

  const int g = g0 + blockIdx.x, tid = threadIdx.x;
  const int nb = g * N_NODES, eb = g * EPG;
  const int lb = blockIdx.x * N_NODES;

  for (int i = tid; i < 1536; i += 256) We_s[i] = We[i];
  for (int i = tid; i < 512; i += 256) att_s[i] = att[i];
  if (tid < HID) b_s[tid] = bias[tid];
  for (int i = tid; i < N_NODES * 1024; i += 256) {
    int s = i >> 10, j = i & 1023;
    float v = xlr[(size_t)(lb + s) * 1024 + j];
    if (j < 512) xl_s[j * N_NODES + s] = v;
    else         xr_s[(j - 512) * N_NODES + s] = v;
  }
  if (tid < EPG) {
    easX[tid] = ea[(eb + tid) * 3 + 0];
    easY[tid] = ea[(eb + tid) * 3 + 1];
    easZ[tid] = ea[(eb + tid) * 3 + 2];
    sloc[tid] = src[eb + tid] - nb;
    dloc[tid] = dst[eb + tid] - nb;
  }
  if (tid < N_NODES) { deg[tid] = 0; fill[tid] = 0; }
  __syncthreads();
  if (tid < EPG) atomicAdd(&deg[dloc[tid]], 1);
  __syncthreads();
  if (tid == 0) { int a = 0; for (int n = 0; n < N_NODES; ++n) { start[n] = a; a += deg[n]; } }
  __syncthreads();
  if (tid < EPG) { int d = dloc[tid]; int p = atomicAdd(&fill[d], 1); elist[start[d] + p] = tid; }

  for (int t = tid; t < EPG * HEADS; t += 256) {
    int h = t >> 6, e = t & 63;
    int s = sloc[e], d = dloc[e];
    float e0 = easX[e], e1 = easY[e], e2 = easZ[e];
    float acc = 0.f;
    int base = h * 64;
    #pragma unroll
    for (int c4 = 0; c4 < 16; ++c4) {
      int j = base + c4 * 4;
      f32x4 we0 = *(const f32x4*)(We_s + j);
      f32x4 we1 = *(const f32x4*)(We_s + 512 + j);
      f32x4 we2 = *(const f32x4*)(We_s + 1024 + j);
      f32x4 at  = *(const f32x4*)(att_s + j);
      #pragma unroll
      for (int q = 0; q < 4; ++q) {
        int jj = j + q;
        float v = xl_s[jj * N_NODES + s] + xr_s[jj * N_NODES + d]
                + e0 * we0[q] + e1 * we1[q] + e2 * we2[q];
        acc += lreluf_(v) * at[q];
      }
    }
    logit_s[h * 65 + e] = acc;
  }
  __syncthreads();

  for (int t = tid; t < HEADS * 64; t += 256) {
    int h = t >> 6, n = t & 63;
    if (n < N_NODES) {
      int s0 = start[n], dn = deg[n];
      float mx = -1e30f;
      for (int i = 0; i < dn; ++i) mx = fmaxf(mx, logit_s[h * 65 + elist[s0 + i]]);
      float den = 0.f;
      for (int i = 0; i < dn; ++i) den += expf(logit_s[h * 65 + elist[s0 + i]] - mx);
      float inv = 1.f / (den + 1e-16f);
      for (int i = 0; i < dn; ++i) {
        int e = elist[s0 + i];
        logit_s[h * 65 + e] = expf(logit_s[h * 65 + e] - mx) * inv;
      }
    }
  }
  __syncthreads();

  for (int t = tid; t < N_NODES * 8; t += 256) {
    int n = t >> 3, jb = t & 7;
    int j0 = jb * 8;
    float acc[8] = {};
    int s0 = start[n], dn = deg[n];
    for (int i = 0; i < dn; ++i) {
      int e = elist[s0 + i]; int s = sloc[e];
      float al[8];
      #pragma unroll
      for (int h = 0; h < 8; ++h) al[h] = logit_s[h * 65 + e];
      #pragma unroll
      for (int cc = 0; cc < 8; ++cc) {
        int c = j0 + cc;
        float sum = 0.f;
        #pragma unroll
        for (int h = 0; h < 8; ++h) sum += al[h] * xl_s[(h * 64 + c) * N_NODES + s];
        acc[cc] += sum;
      }
    }
    bf16x8 vh, vl;
    #pragma unroll
    for (int cc = 0; cc < 8; ++cc) {
      float v = eluf_(acc[cc] * 0.125f + b_s[j0 + cc]);
      short hb = f2bf(v);
      vh[cc] = hb;
      vl[cc] = f2bf(v - bf2f(hb));
    }
    size_t o = (size_t)(nb + n) * HID + j0;
    *(bf16x8*)(h2hi + o) = vh;
    *(bf16x8*)(h2lo + o) = vl;
  }
}

// ============================================================
// LSTM1 (round-5 no-spill version) + rest of the chain
// ============================================================
__global__ __launch_bounds__(1024, 4) void lstm1_kernel(
    const float* __restrict__ X, const float* __restrict__ Whh, float* __restrict__ Y) {
  __shared__ float hs[LSTM1_H], cs[LSTM1_H], part[4 * LSTM1_H], gs[4 * LSTM1_H];
  const int tid = threadIdx.x;
  const int j = tid & 511, half = tid >> 9;
  const int b = blockIdx.x;
  float4 w[16];
  const float4* wp = (const float4*)(Whh + (size_t)j * LSTM1_H + half * 64);
  #pragma unroll
  for (int q = 0; q < 16; ++q) w[q] = wp[q];
  if (tid < LSTM1_H) { hs[tid] = 0.f; cs[tid] = 0.f; }
  __syncthreads();
  for (int t = 0; t < SEQ; ++t) {
    const float* hb = hs + half * 64;
    float acc = 0.f;
    #pragma unroll
    for (int q = 0; q < 16; ++q) {
      acc += w[q].x * hb[4 * q] + w[q].y * hb[4 * q + 1]
           + w[q].z * hb[4 * q + 2] + w[q].w * hb[4 * q + 3];
    }
    if (half) part[j] = acc;
    __syncthreads();
    if (!half) gs[j] = acc + part[j] + X[((size_t)b * SEQ + t) * 512 + j];
    __syncthreads();
    if (tid < LSTM1_H) {
      float ig = sigmoidf_(gs[tid]);
      float fg = sigmoidf_(gs[LSTM1_H + tid]);
      float gg = tanhf(gs[2 * LSTM1_H + tid]);
      float og = sigmoidf_(gs[3 * LSTM1_H + tid]);
      float c = fg * cs[tid] + ig * gg;
      cs[tid] = c;
      float h = og * tanhf(c);
      hs[tid] = h;
      Y[((size_t)b * SEQ + t) * LSTM1_H + tid] = h;
    }
    __syncthreads();
  }
}

__global__ __launch_bounds__(256) void x2_kernel(
    const float* __restrict__ Y1, const float* __restrict__ Wih,
    const float* __restrict__ bih, const float* __restrict__ bhh,
    float* __restrict__ X2) {
  __shared__ float ys[LSTM1_H];
  const int g = blockIdx.x, j = threadIdx.x;
  if (j < LSTM1_H) ys[j] = Y1[(size_t)g * LSTM1_H + j];
  __syncthreads();
  const float4* wp = (const float4*)(Wih + (size_t)j * LSTM1_H);
  float acc = bih[j] + bhh[j];
  #pragma unroll
  for (int q = 0; q < 32; ++q) {
    float4 w = wp[q];
    acc += w.x * ys[4 * q] + w.y * ys[4 * q + 1] + w.z * ys[4 * q + 2] + w.w * ys[4 * q + 3];
  }
  X2[(size_t)g * 256 + j] = acc;
}

__global__ __launch_bounds__(256, 2) void lstm2_fc_kernel(
    const float* __restrict__ X, const float* __restrict__ Whh,
    const float* __restrict__ fcW, const float* __restrict__ fcb,
    float* __restrict__ out) {
  __shared__ float hs[LSTM2_H], cs[LSTM2_H], gs[4 * LSTM2_H];
  const int b = blockIdx.x, j = threadIdx.x;
  float4 w[16];
  const float4* wp = (const float4*)(Whh + (size_t)j * LSTM2_H);
  #pragma unroll
  for (int q = 0; q < 16; ++q) w[q] = wp[q];
  if (j < LSTM2_H) { hs[j] = 0.f; cs[j] = 0.f; }
  __syncthreads();
  for (int t = 0; t < SEQ; ++t) {
    float acc = X[((size_t)b * SEQ + t) * 256 + j];
    #pragma unroll
    for (int q = 0; q < 16; ++q) {
      acc += w[q].x * hs[4 * q] + w[q].y * hs[4 * q + 1]
           + w[q].z * hs[4 * q + 2] + w[q].w * hs[4 * q + 3];
    }
    gs[j] = acc;
    __syncthreads();
    if (j < LSTM2_H) {
      float ig = sigmoidf_(gs[j]);
      float fg = sigmoidf_(gs[LSTM2_H + j]);
      float gg = tanhf(gs[2 * LSTM2_H + j]);
      float og = sigmoidf_(gs[3 * LSTM2_H + j]);
      float c = fg * cs[j] + ig * gg;
      cs[j] = c;
      hs[j] = og * tanhf(c);
    }
    __syncthreads();
  }
  if (j < 4) {
    float acc = fcb[j];
    #pragma unroll
    for (int k = 0; k < LSTM2_H; ++k) acc += fcW[j * LSTM2_H + k] * hs[k];
    out[b * 4 + j] = acc;
  }
}

// ============================================================
extern "C" void kernel_launch(void* const* d_in, const int* in_sizes, int n_in,
                              void* d_out, int out_size, void* d_ws, size_t ws_size,
                              hipStream_t stream) {
  const float* x       = (const float*)d_in[0];
  const int*   eidx    = (const int*)d_in[1];
  const float* eattr   = (const float*)d_in[2];
  const float* g1_Wl   = (const float*)d_in[3];
  const float* g1_Wr   = (const float*)d_in[4];
  const float* g1_We   = (const float*)d_in[5];
  const float* g1_att  = (const float*)d_in[6];
  const float* g1_b    = (const float*)d_in[7];
  const float* g2_Wl   = (const float*)d_in[8];
  const float* g2_Wr   = (const float*)d_in[9];
  const float* g2_We   = (const float*)d_in[10];
  const float* g2_att  = (const float*)d_in[11];
  const float* g2_b    = (const float*)d_in[12];
  const float* l1_Wih  = (const float*)d_in[13];
  const float* l1_Whh  = (const float*)d_in[14];
  const float* l1_bih  = (const float*)d_in[15];
  const float* l1_bhh  = (const float*)d_in[16];
  const float* l2_Wih  = (const float*)d_in[17];
  const float* l2_Whh  = (const float*)d_in[18];
  const float* l2_bih  = (const float*)d_in[19];
  const float* l2_bhh  = (const float*)d_in[20];
  const float* fc_W    = (const float*)d_in[21];
  const float* fc_b    = (const float*)d_in[22];
  float* out = (float*)d_out;

  const int* src = eidx;
  const int* dst = eidx + E_EDGES;

  // ---- workspace layout (256B-aligned chunks), peak ~77 MB ----
  char* p = (char*)d_ws;
  auto alloc = [&](size_t bytes) { char* r = p; p += (bytes + 255) & ~(size_t)255; return r; };
  short* h1hi  = (short*)alloc((size_t)CHUNK_N * HC * 2);
  short* h1lo  = (short*)alloc((size_t)CHUNK_N * HC * 2);
  float* xlr2c = (float*)alloc((size_t)CHUNK_N * 1024 * 4);
  short* h2hi  = (short*)alloc((size_t)G_GRAPHS * 2112 * 2);
  short* h2lo  = (short*)alloc((size_t)G_GRAPHS * 2112 * 2);
  short* B2hi  = (short*)alloc((size_t)1024 * 512 * 2);
  short* B2lo  = (short*)alloc((size_t)1024 * 512 * 2);
  short* W1hi  = (short*)alloc((size_t)512 * 2112 * 2);
  short* W1lo  = (short*)alloc((size_t)512 * 2112 * 2);
  float* X1    = (float*)alloc((size_t)G_GRAPHS * 512 * 4);
  float* Y1    = (float*)alloc((size_t)G_GRAPHS * LSTM1_H * 4);
  float* X2    = (float*)alloc((size_t)G_GRAPHS * 256 * 4);
  size_t needed = (size_t)(p - (char*)d_ws);
  if (ws_size < needed) return;   // guard: zero output instead of memory fault

  conv_g2w<<<(1024 * 512) / 256, 256, 0, stream>>>(g2_Wl, g2_Wr, B2hi, B2lo);
  conv_w1<<<(512 * 2112 + 255) / 256, 256, 0, stream>>>(l1_Wih, W1hi, W1lo, 512 * 2112);

  for (int c = 0; c < N_CHUNKS; ++c) {
    int g0 = c * CHUNK_G;
    gat1_kernel<<<CHUNK_G, 256, 0, stream>>>(x, src, dst, eattr, g1_Wl, g1_Wr, g1_We,
                                             g1_att, g1_b, h1hi, h1lo, g0);
    // barrier-free A-stationary GEMM: grid (N/128, M/32) = (8, 264)
    dim3 grid(1024 / 128, CHUNK_N / 32);
    gemm_as512<<<grid, 256, 0, stream>>>(h1hi, h1lo, B2hi, B2lo, xlr2c,
                                         CHUNK_N, 1024);
    gat2_kernel<<<CHUNK_G, 256, 0, stream>>>(xlr2c, src, dst, eattr, g2_We,
                                             g2_att, g2_b, h2hi, h2lo, g0);
  }

  {
    dim3 grid(512 / 64, G_GRAPHS / 64);
    gemm_mfma<2, 2><<<grid, 256, 0, stream>>>(h2hi, h2lo, W1hi, W1lo, X1,
                                              l1_bih, l1_bhh,
                                              G_GRAPHS, 512, N_NODES * HID);
  }

  lstm1_kernel<<<BATCH, 1024, 0, stream>>>(X1, l1_Whh, Y1);
  x2_kernel<<<G_GRAPHS, 256, 0, stream>>>(Y1, l2_Wih, l2_bih, l2_bhh, X2);
  lstm2_fc_kernel<<<BATCH, 256, 0, stream>>>(X2, l2_Whh, fc_W, fc_b, out);
}

// Round 7
// 804.051 us; speedup vs baseline: 1.7626x; 1.7626x over previous
//
#include <hip/hip_runtime.h>
#include <math.h>

// ---- problem constants ----
#define N_NODES 33
#define SEQ 24
#define BATCH 64
#define G_GRAPHS (BATCH * SEQ)          // 1536
#define EPG 64
#define E_EDGES (G_GRAPHS * EPG)        // 98304
#define N_TOTAL (G_GRAPHS * N_NODES)    // 50688
#define HID 64
#define HEADS 8
#define HC (HID * HEADS)                // 512
#define LSTM1_H 128
#define LSTM2_H 64
#define NEG_SLOPE 0.2f

// graph chunking: 6 chunks of 256 graphs keeps peak ws ~77 MB (<96.3 MB known-safe)
#define N_CHUNKS 6
#define CHUNK_G (G_GRAPHS / N_CHUNKS)   // 256 graphs
#define CHUNK_N (CHUNK_G * N_NODES)     // 8448 nodes

__device__ __forceinline__ float sigmoidf_(float x) { return 1.f / (1.f + expf(-x)); }
__device__ __forceinline__ float eluf_(float x) { return x > 0.f ? x : expm1f(x); }
__device__ __forceinline__ float lreluf_(float x) { return x > 0.f ? x : NEG_SLOPE * x; }

// bf16 (RNE) pack/unpack on raw shorts
__device__ __forceinline__ short f2bf(float x) {
  unsigned u = __float_as_uint(x);
  unsigned r = (u + 0x7fffu + ((u >> 16) & 1u)) >> 16;
  return (short)r;
}
__device__ __forceinline__ float bf2f(short b) {
  return __uint_as_float(((unsigned)(unsigned short)b) << 16);
}

typedef __attribute__((ext_vector_type(8))) short bf16x8;
typedef __attribute__((ext_vector_type(4))) float f32x4;

__device__ __forceinline__ void gl2lds16(const void* g, void* l) {
  __builtin_amdgcn_global_load_lds(
      (__attribute__((address_space(1))) const unsigned int*)g,
      (__attribute__((address_space(3))) unsigned int*)l, 16, 0, 0);
}

// ============================================================
// GAT layer 1 (round-4 version — conflict-free, verified)
// ============================================================
__global__ __launch_bounds__(256) void gat1_kernel(
    const float* __restrict__ x, const int* __restrict__ src, const int* __restrict__ dst,
    const float* __restrict__ ea, const float* __restrict__ Wl, const float* __restrict__ Wr,
    const float* __restrict__ We, const float* __restrict__ att, const float* __restrict__ bias,
    short* __restrict__ h1hi, short* __restrict__ h1lo, int g0) {
  __shared__ alignas(16) float Wl_s[2 * 512];
  __shared__ alignas(16) float Wr_s[2 * 512];
  __shared__ alignas(16) float We_s[3 * 512];
  __shared__ alignas(16) float att_s[512];
  __shared__ float xs0_s[N_NODES + 1], xs1_s[N_NODES + 1];
  __shared__ float easX[EPG], easY[EPG], easZ[EPG];
  __shared__ float logit_s[HEADS * 65];   // padded stride 65
  __shared__ int sloc[EPG], dloc[EPG], deg[N_NODES], start[N_NODES], fill[N_NODES], elist[EPG];

  const int g = g0 + blockIdx.x, tid = threadIdx.x;
  const int nb = g * N_NODES, eb = g * EPG;
  const int lb = blockIdx.x * N_NODES;

  for (int i = tid; i < 1024; i += 256) { Wl_s[i] = Wl[i]; Wr_s[i] = Wr[i]; }
  for (int i = tid; i < 1536; i += 256) We_s[i] = We[i];
  for (int i = tid; i < 512; i += 256) att_s[i] = att[i];
  if (tid < 2 * N_NODES) {
    float v = x[nb * 2 + tid];
    if (tid & 1) xs1_s[tid >> 1] = v; else xs0_s[tid >> 1] = v;
  }
  if (tid < EPG) {
    easX[tid] = ea[(eb + tid) * 3 + 0];
    easY[tid] = ea[(eb + tid) * 3 + 1];
    easZ[tid] = ea[(eb + tid) * 3 + 2];
    sloc[tid] = src[eb + tid] - nb;
    dloc[tid] = dst[eb + tid] - nb;
  }
  if (tid < N_NODES) { deg[tid] = 0; fill[tid] = 0; }
  __syncthreads();
  if (tid < EPG) atomicAdd(&deg[dloc[tid]], 1);
  __syncthreads();
  if (tid == 0) { int a = 0; for (int n = 0; n < N_NODES; ++n) { start[n] = a; a += deg[n]; } }
  __syncthreads();
  if (tid < EPG) { int d = dloc[tid]; int p = atomicAdd(&fill[d], 1); elist[start[d] + p] = tid; }

  // logits: h = t>>6 (wave-uniform), e = t&63 (= lane). Weight reads broadcast.
  for (int t = tid; t < EPG * HEADS; t += 256) {
    int h = t >> 6, e = t & 63;
    int s = sloc[e], d = dloc[e];
    float xs0 = xs0_s[s], xs1 = xs1_s[s], xd0 = xs0_s[d], xd1 = xs1_s[d];
    float e0 = easX[e], e1 = easY[e], e2 = easZ[e];
    float acc = 0.f;
    int base = h * 64;
    #pragma unroll
    for (int c4 = 0; c4 < 16; ++c4) {
      int j = base + c4 * 4;
      f32x4 wl0 = *(const f32x4*)(Wl_s + j);
      f32x4 wl1 = *(const f32x4*)(Wl_s + 512 + j);
      f32x4 wr0 = *(const f32x4*)(Wr_s + j);
      f32x4 wr1 = *(const f32x4*)(Wr_s + 512 + j);
      f32x4 we0 = *(const f32x4*)(We_s + j);
      f32x4 we1 = *(const f32x4*)(We_s + 512 + j);
      f32x4 we2 = *(const f32x4*)(We_s + 1024 + j);
      f32x4 at  = *(const f32x4*)(att_s + j);
      #pragma unroll
      for (int q = 0; q < 4; ++q) {
        float v = xs0 * wl0[q] + xs1 * wl1[q]
                + xd0 * wr0[q] + xd1 * wr1[q]
                + e0 * we0[q] + e1 * we1[q] + e2 * we2[q];
        acc += lreluf_(v) * at[q];
      }
    }
    logit_s[h * 65 + e] = acc;
  }
  __syncthreads();

  // segment softmax: h = t>>6 (uniform), n = t&63 (lane), skip n>=33
  for (int t = tid; t < HEADS * 64; t += 256) {
    int h = t >> 6, n = t & 63;
    if (n < N_NODES) {
      int s0 = start[n], dn = deg[n];
      float mx = -1e30f;
      for (int i = 0; i < dn; ++i) mx = fmaxf(mx, logit_s[h * 65 + elist[s0 + i]]);
      float den = 0.f;
      for (int i = 0; i < dn; ++i) den += expf(logit_s[h * 65 + elist[s0 + i]] - mx);
      float inv = 1.f / (den + 1e-16f);
      for (int i = 0; i < dn; ++i) {
        int e = elist[s0 + i];
        logit_s[h * 65 + e] = expf(logit_s[h * 65 + e] - mx) * inv;
      }
    }
  }
  __syncthreads();

  // aggregation: task = (n, 8-channel block). n = t>>6 wave-uniform, jb = lane.
  for (int t = tid; t < N_NODES * 64; t += 256) {
    int n = t >> 6, jb = t & 63;
    int j0 = jb * 8, h = jb >> 3;
    f32x4 wa0 = *(const f32x4*)(Wl_s + j0);
    f32x4 wa1 = *(const f32x4*)(Wl_s + j0 + 4);
    f32x4 wb0 = *(const f32x4*)(Wl_s + 512 + j0);
    f32x4 wb1 = *(const f32x4*)(Wl_s + 512 + j0 + 4);
    float acc[8] = {};
    int s0 = start[n], dn = deg[n];
    for (int i = 0; i < dn; ++i) {
      int e = elist[s0 + i]; int s = sloc[e];
      float a = logit_s[h * 65 + e];
      float ax0 = a * xs0_s[s], ax1 = a * xs1_s[s];
      #pragma unroll
      for (int q = 0; q < 4; ++q) {
        acc[q]     += ax0 * wa0[q] + ax1 * wb0[q];
        acc[4 + q] += ax0 * wa1[q] + ax1 * wb1[q];
      }
    }
    f32x4 b0 = *(const f32x4*)(bias + j0);
    f32x4 b1 = *(const f32x4*)(bias + j0 + 4);
    bf16x8 vh, vl;
    #pragma unroll
    for (int cc = 0; cc < 8; ++cc) {
      float bb = (cc < 4) ? b0[cc] : b1[cc - 4];
      float v = eluf_(acc[cc] + bb);
      short hb = f2bf(v);
      vh[cc] = hb;
      vl[cc] = f2bf(v - bf2f(hb));
    }
    size_t o = (size_t)(lb + n) * HC + j0;
    *(bf16x8*)(h1hi + o) = vh;
    *(bf16x8*)(h1lo + o) = vl;
  }
}

// ============================================================
// weight conversion kernels (unchanged)
// ============================================================
__global__ __launch_bounds__(256) void conv_g2w(
    const float* __restrict__ Wl, const float* __restrict__ Wr,
    short* __restrict__ Bhi, short* __restrict__ Blo) {
  int idx = blockIdx.x * 256 + threadIdx.x;
  int n = idx >> 9, k = idx & 511;
  float v = (n < 512) ? Wl[k * 512 + n] : Wr[k * 512 + (n - 512)];
  short hi = f2bf(v);
  Bhi[idx] = hi;
  Blo[idx] = f2bf(v - bf2f(hi));
}

__global__ __launch_bounds__(256) void conv_w1(
    const float* __restrict__ W, short* __restrict__ Whi, short* __restrict__ Wlo, int total) {
  int idx = blockIdx.x * 256 + threadIdx.x;
  if (idx >= total) return;
  float v = W[idx];
  short hi = f2bf(v);
  Whi[idx] = hi;
  Wlo[idx] = f2bf(v - bf2f(hi));
}

// ============================================================
// split-bf16 MFMA GEMM, BK=64 as two 32-wide panels per barrier.
// Round-5 (BK=32) ran 49.4 us on the 8448x1024x512 chunk GEMM, MfmaUtil 21%,
// barrier-drain-bound. Two panels => 24 MFMAs per barrier instead of 12,
// identical (proven) per-panel LDS addressing. LDS = (BM+BN)*64*2 shorts
// = 32 KB at BM=BN=64. K must be divisible by 64 (512, 2112 both are).
// ROUND-6 LESSON: do NOT stream an MFMA operand global->VGPR (gemm_as512:
// 144 us, MfmaUtil 7% — scattered 64B segments, latency-serialized).
// ============================================================
template <int WM, int WN>
__global__ __launch_bounds__(256) void gemm_mfma(
    const short* __restrict__ Ahi, const short* __restrict__ Alo,
    const short* __restrict__ Bhi, const short* __restrict__ Blo,
    float* __restrict__ C, const float* __restrict__ bias1, const float* __restrict__ bias2,
    int M, int N, int K) {
  constexpr int BM = 32 * WM, BN = 32 * WN;
  __shared__ short lds[(BM + BN) * 2 * 64];
  short* Ah_s = lds;                    // [2][BM][32]
  short* Al_s = Ah_s + BM * 64;
  short* Bh_s = Al_s + BM * 64;         // [2][BN][32]
  short* Bl_s = Bh_s + BN * 64;

  const int tid = threadIdx.x;
  const int wave = tid >> 6, lane = tid & 63;
  const int wm = wave >> 1, wn = wave & 1;
  const int bm = blockIdx.y * BM, bn = blockIdx.x * BN;

  const int rA = lane >> 2;          // 0..15
  const int cA = (lane & 3) * 8;     // 16B unit within 32-k panel row

  f32x4 acc[WM][WN];
  #pragma unroll
  for (int tm = 0; tm < WM; ++tm)
    #pragma unroll
    for (int tn = 0; tn < WN; ++tn) acc[tm][tn] = {0.f, 0.f, 0.f, 0.f};

  for (int k0 = 0; k0 < K; k0 += 64) {
    #pragma unroll
    for (int p = 0; p < 2; ++p) {
      int kk = k0 + p * 32;
      #pragma unroll
      for (int i = 0; i < BM / 64; ++i) {
        int row = i * 64 + wave * 16;
        size_t go = (size_t)(bm + row + rA) * K + kk + cA;
        int lo = p * BM * 32 + row * 32;
        gl2lds16(Ahi + go, Ah_s + lo);
        gl2lds16(Alo + go, Al_s + lo);
      }
      #pragma unroll
      for (int i = 0; i < BN / 64; ++i) {
        int row = i * 64 + wave * 16;
        size_t go = (size_t)(bn + row + rA) * K + kk + cA;
        int lo = p * BN * 32 + row * 32;
        gl2lds16(Bhi + go, Bh_s + lo);
        gl2lds16(Blo + go, Bl_s + lo);
      }
    }
    __syncthreads();

    const int fr = lane & 15;
    const int fk = (lane >> 4) * 8;
    #pragma unroll
    for (int p = 0; p < 2; ++p) {
      const int pA = p * BM * 32, pB = p * BN * 32;
      bf16x8 a_h[WM], a_l[WM], b_h[WN], b_l[WN];
      #pragma unroll
      for (int tm = 0; tm < WM; ++tm) {
        int r = (wm * WM + tm) * 16 + fr;
        a_h[tm] = *(const bf16x8*)(Ah_s + pA + r * 32 + fk);
        a_l[tm] = *(const bf16x8*)(Al_s + pA + r * 32 + fk);
      }
      #pragma unroll
      for (int tn = 0; tn < WN; ++tn) {
        int r = (wn * WN + tn) * 16 + fr;
        b_h[tn] = *(const bf16x8*)(Bh_s + pB + r * 32 + fk);
        b_l[tn] = *(const bf16x8*)(Bl_s + pB + r * 32 + fk);
      }
      #pragma unroll
      for (int tm = 0; tm < WM; ++tm)
        #pragma unroll
        for (int tn = 0; tn < WN; ++tn) {
          acc[tm][tn] = __builtin_amdgcn_mfma_f32_16x16x32_bf16(a_h[tm], b_h[tn], acc[tm][tn], 0, 0, 0);
          acc[tm][tn] = __builtin_amdgcn_mfma_f32_16x16x32_bf16(a_h[tm], b_l[tn], acc[tm][tn], 0, 0, 0);
          acc[tm][tn] = __builtin_amdgcn_mfma_f32_16x16x32_bf16(a_l[tm], b_h[tn], acc[tm][tn], 0, 0, 0);
        }
    }
    __syncthreads();
  }

  // epilogue: C/D layout col=lane&15, row=(lane>>4)*4+reg  [m89/m91 verified]
  const int col0 = lane & 15, rq = (lane >> 4) * 4;
  #pragma unroll
  for (int tm = 0; tm < WM; ++tm)
    #pragma unroll
    for (int tn = 0; tn < WN; ++tn) {
      int col = bn + (wn * WN + tn) * 16 + col0;
      float badd = 0.f;
      if (bias1) badd += bias1[col];
      if (bias2) badd += bias2[col];
      #pragma unroll
      for (int r = 0; r < 4; ++r) {
        int row = bm + (wm * WM + tm) * 16 + rq + r;
        C[(size_t)row * N + col] = acc[tm][tn][r] + badd;
      }
    }
}

// ============================================================
// GAT layer 2 (round-4 version — verified)
// ============================================================
__global__ __launch_bounds__(256) void gat2_kernel(
    const float* __restrict__ xlr, const int* __restrict__ src, const int* __restrict__ dst,
    const float* __restrict__ ea, const float* __restrict__ We,
    const float* __restrict__ att, const float* __restrict__ bias,
    short* __restrict__ h2hi, short* __restrict__ h2lo, int g0) {
  __shared__ float xl_s[512 * N_NODES];   // [j][s]
  __shared__ float xr_s[512 * N_NODES];   // [j][d]
  __shared__ alignas(16) float We_s[3 * 512];
  __shared__ alignas(16) float att_s[512];
  __shared__ float b_s[HID];
  __shared__ float easX[EPG], easY[EPG], easZ[EPG];
  __shared__ float logit_s[HEADS * 65];
  __shared__ int sloc[EPG], dloc[EPG], deg[N_NODES], start[N_NODES], fill[N_NODES], elist[EPG];

  const int g = g0 + blockIdx.x, tid = threadIdx.x;
  const int nb = g * N_NODES, eb = g * EPG;
  const int lb = blockIdx.x * N_NODES;

  for (int i = tid; i < 1536; i += 256) We_s[i] = We[i];
  for (int i = tid; i < 512; i += 256) att_s[i] = att[i];
  if (tid < HID) b_s[tid] = bias[tid];
  for (int i = tid; i < N_NODES * 1024; i += 256) {
    int s = i >> 10, j = i & 1023;
    float v = xlr[(size_t)(lb + s) * 1024 + j];
    if (j < 512) xl_s[j * N_NODES + s] = v;
    else         xr_s[(j - 512) * N_NODES + s] = v;
  }
  if (tid < EPG) {
    easX[tid] = ea[(eb + tid) * 3 + 0];
    easY[tid] = ea[(eb + tid) * 3 + 1];
    easZ[tid] = ea[(eb + tid) * 3 + 2];
    sloc[tid] = src[eb + tid] - nb;
    dloc[tid] = dst[eb + tid] - nb;
  }
  if (tid < N_NODES) { deg[tid] = 0; fill[tid] = 0; }
  __syncthreads();
  if (tid < EPG) atomicAdd(&deg[dloc[tid]], 1);
  __syncthreads();
  if (tid == 0) { int a = 0; for (int n = 0; n < N_NODES; ++n) { start[n] = a; a += deg[n]; } }
  __syncthreads();
  if (tid < EPG) { int d = dloc[tid]; int p = atomicAdd(&fill[d], 1); elist[start[d] + p] = tid; }

  for (int t = tid; t < EPG * HEADS; t += 256) {
    int h = t >> 6, e = t & 63;
    int s = sloc[e], d = dloc[e];
    float e0 = easX[e], e1 = easY[e], e2 = easZ[e];
    float acc = 0.f;
    int base = h * 64;
    #pragma unroll
    for (int c4 = 0; c4 < 16; ++c4) {
      int j = base + c4 * 4;
      f32x4 we0 = *(const f32x4*)(We_s + j);
      f32x4 we1 = *(const f32x4*)(We_s + 512 + j);
      f32x4 we2 = *(const f32x4*)(We_s + 1024 + j);
      f32x4 at  = *(const f32x4*)(att_s + j);
      #pragma unroll
      for (int q = 0; q < 4; ++q) {
        int jj = j + q;
        float v = xl_s[jj * N_NODES + s] + xr_s[jj * N_NODES + d]
                + e0 * we0[q] + e1 * we1[q] + e2 * we2[q];
        acc += lreluf_(v) * at[q];
      }
    }
    logit_s[h * 65 + e] = acc;
  }
  __syncthreads();

  for (int t = tid; t < HEADS * 64; t += 256) {
    int h = t >> 6, n = t & 63;
    if (n < N_NODES) {
      int s0 = start[n], dn = deg[n];
      float mx = -1e30f;
      for (int i = 0; i < dn; ++i) mx = fmaxf(mx, logit_s[h * 65 + elist[s0 + i]]);
      float den = 0.f;
      for (int i = 0; i < dn; ++i) den += expf(logit_s[h * 65 + elist[s0 + i]] - mx);
      float inv = 1.f / (den + 1e-16f);
      for (int i = 0; i < dn; ++i) {
        int e = elist[s0 + i];
        logit_s[h * 65 + e] = expf(logit_s[h * 65 + e] - mx) * inv;
      }
    }
  }
  __syncthreads();

  for (int t = tid; t < N_NODES * 8; t += 256) {
    int n = t >> 3, jb = t & 7;
    int j0 = jb * 8;
    float acc[8] = {};
    int s0 = start[n], dn = deg[n];
    for (int i = 0; i < dn; ++i) {
      int e = elist[s0 + i]; int s = sloc[e];
      float al[8];
      #pragma unroll
      for (int h = 0; h < 8; ++h) al[h] = logit_s[h * 65 + e];
      #pragma unroll
      for (int cc = 0; cc < 8; ++cc) {
        int c = j0 + cc;
        float sum = 0.f;
        #pragma unroll
        for (int h = 0; h < 8; ++h) sum += al[h] * xl_s[(h * 64 + c) * N_NODES + s];
        acc[cc] += sum;
      }
    }
    bf16x8 vh, vl;
    #pragma unroll
    for (int cc = 0; cc < 8; ++cc) {
      float v = eluf_(acc[cc] * 0.125f + b_s[j0 + cc]);
      short hb = f2bf(v);
      vh[cc] = hb;
      vl[cc] = f2bf(v - bf2f(hb));
    }
    size_t o = (size_t)(nb + n) * HID + j0;
    *(bf16x8*)(h2hi + o) = vh;
    *(bf16x8*)(h2lo + o) = vl;
  }
}

// ============================================================
// LSTM1 (round-5 no-spill version) + rest of the chain
// ============================================================
__global__ __launch_bounds__(1024, 4) void lstm1_kernel(
    const float* __restrict__ X, const float* __restrict__ Whh, float* __restrict__ Y) {
  __shared__ float hs[LSTM1_H], cs[LSTM1_H], part[4 * LSTM1_H], gs[4 * LSTM1_H];
  const int tid = threadIdx.x;
  const int j = tid & 511, half = tid >> 9;
  const int b = blockIdx.x;
  float4 w[16];
  const float4* wp = (const float4*)(Whh + (size_t)j * LSTM1_H + half * 64);
  #pragma unroll
  for (int q = 0; q < 16; ++q) w[q] = wp[q];
  if (tid < LSTM1_H) { hs[tid] = 0.f; cs[tid] = 0.f; }
  __syncthreads();
  for (int t = 0; t < SEQ; ++t) {
    const float* hb = hs + half * 64;
    float acc = 0.f;
    #pragma unroll
    for (int q = 0; q < 16; ++q) {
      acc += w[q].x * hb[4 * q] + w[q].y * hb[4 * q + 1]
           + w[q].z * hb[4 * q + 2] + w[q].w * hb[4 * q + 3];
    }
    if (half) part[j] = acc;
    __syncthreads();
    if (!half) gs[j] = acc + part[j] + X[((size_t)b * SEQ + t) * 512 + j];
    __syncthreads();
    if (tid < LSTM1_H) {
      float ig = sigmoidf_(gs[tid]);
      float fg = sigmoidf_(gs[LSTM1_H + tid]);
      float gg = tanhf(gs[2 * LSTM1_H + tid]);
      float og = sigmoidf_(gs[3 * LSTM1_H + tid]);
      float c = fg * cs[tid] + ig * gg;
      cs[tid] = c;
      float h = og * tanhf(c);
      hs[tid] = h;
      Y[((size_t)b * SEQ + t) * LSTM1_H + tid] = h;
    }
    __syncthreads();
  }
}

__global__ __launch_bounds__(256) void x2_kernel(
    const float* __restrict__ Y1, const float* __restrict__ Wih,
    const float* __restrict__ bih, const float* __restrict__ bhh,
    float* __restrict__ X2) {
  __shared__ float ys[LSTM1_H];
  const int g = blockIdx.x, j = threadIdx.x;
  if (j < LSTM1_H) ys[j] = Y1[(size_t)g * LSTM1_H + j];
  __syncthreads();
  const float4* wp = (const float4*)(Wih + (size_t)j * LSTM1_H);
  float acc = bih[j] + bhh[j];
  #pragma unroll
  for (int q = 0; q < 32; ++q) {
    float4 w = wp[q];
    acc += w.x * ys[4 * q] + w.y * ys[4 * q + 1] + w.z * ys[4 * q + 2] + w.w * ys[4 * q + 3];
  }
  X2[(size_t)g * 256 + j] = acc;
}

__global__ __launch_bounds__(256, 2) void lstm2_fc_kernel(
    const float* __restrict__ X, const float* __restrict__ Whh,
    const float* __restrict__ fcW, const float* __restrict__ fcb,
    float* __restrict__ out) {
  __shared__ float hs[LSTM2_H], cs[LSTM2_H], gs[4 * LSTM2_H];
  const int b = blockIdx.x, j = threadIdx.x;
  float4 w[16];
  const float4* wp = (const float4*)(Whh + (size_t)j * LSTM2_H);
  #pragma unroll
  for (int q = 0; q < 16; ++q) w[q] = wp[q];
  if (j < LSTM2_H) { hs[j] = 0.f; cs[j] = 0.f; }
  __syncthreads();
  for (int t = 0; t < SEQ; ++t) {
    float acc = X[((size_t)b * SEQ + t) * 256 + j];
    #pragma unroll
    for (int q = 0; q < 16; ++q) {
      acc += w[q].x * hs[4 * q] + w[q].y * hs[4 * q + 1]
           + w[q].z * hs[4 * q + 2] + w[q].w * hs[4 * q + 3];
    }
    gs[j] = acc;
    __syncthreads();
    if (j < LSTM2_H) {
      float ig = sigmoidf_(gs[j]);
      float fg = sigmoidf_(gs[LSTM2_H + j]);
      float gg = tanhf(gs[2 * LSTM2_H + j]);
      float og = sigmoidf_(gs[3 * LSTM2_H + j]);
      float c = fg * cs[j] + ig * gg;
      cs[j] = c;
      hs[j] = og * tanhf(c);
    }
    __syncthreads();
  }
  if (j < 4) {
    float acc = fcb[j];
    #pragma unroll
    for (int k = 0; k < LSTM2_H; ++k) acc += fcW[j * LSTM2_H + k] * hs[k];
    out[b * 4 + j] = acc;
  }
}

// ============================================================
extern "C" void kernel_launch(void* const* d_in, const int* in_sizes, int n_in,
                              void* d_out, int out_size, void* d_ws, size_t ws_size,
                              hipStream_t stream) {
  const float* x       = (const float*)d_in[0];
  const int*   eidx    = (const int*)d_in[1];
  const float* eattr   = (const float*)d_in[2];
  const float* g1_Wl   = (const float*)d_in[3];
  const float* g1_Wr   = (const float*)d_in[4];
  const float* g1_We   = (const float*)d_in[5];
  const float* g1_att  = (const float*)d_in[6];
  const float* g1_b    = (const float*)d_in[7];
  const float* g2_Wl   = (const float*)d_in[8];
  const float* g2_Wr   = (const float*)d_in[9];
  const float* g2_We   = (const float*)d_in[10];
  const float* g2_att  = (const float*)d_in[11];
  const float* g2_b    = (const float*)d_in[12];
  const float* l1_Wih  = (const float*)d_in[13];
  const float* l1_Whh  = (const float*)d_in[14];
  const float* l1_bih  = (const float*)d_in[15];
  const float* l1_bhh  = (const float*)d_in[16];
  const float* l2_Wih  = (const float*)d_in[17];
  const float* l2_Whh  = (const float*)d_in[18];
  const float* l2_bih  = (const float*)d_in[19];
  const float* l2_bhh  = (const float*)d_in[20];
  const float* fc_W    = (const float*)d_in[21];
  const float* fc_b    = (const float*)d_in[22];
  float* out = (float*)d_out;

  const int* src = eidx;
  const int* dst = eidx + E_EDGES;

  // ---- workspace layout (256B-aligned chunks), peak ~77 MB ----
  char* p = (char*)d_ws;
  auto alloc = [&](size_t bytes) { char* r = p; p += (bytes + 255) & ~(size_t)255; return r; };
  short* h1hi  = (short*)alloc((size_t)CHUNK_N * HC * 2);
  short* h1lo  = (short*)alloc((size_t)CHUNK_N * HC * 2);
  float* xlr2c = (float*)alloc((size_t)CHUNK_N * 1024 * 4);
  short* h2hi  = (short*)alloc((size_t)G_GRAPHS * 2112 * 2);
  short* h2lo  = (short*)alloc((size_t)G_GRAPHS * 2112 * 2);
  short* B2hi  = (short*)alloc((size_t)1024 * 512 * 2);
  short* B2lo  = (short*)alloc((size_t)1024 * 512 * 2);
  short* W1hi  = (short*)alloc((size_t)512 * 2112 * 2);
  short* W1lo  = (short*)alloc((size_t)512 * 2112 * 2);
  float* X1    = (float*)alloc((size_t)G_GRAPHS * 512 * 4);
  float* Y1    = (float*)alloc((size_t)G_GRAPHS * LSTM1_H * 4);
  float* X2    = (float*)alloc((size_t)G_GRAPHS * 256 * 4);
  size_t needed = (size_t)(p - (char*)d_ws);
  if (ws_size < needed) return;   // guard: zero output instead of memory fault

  conv_g2w<<<(1024 * 512) / 256, 256, 0, stream>>>(g2_Wl, g2_Wr, B2hi, B2lo);
  conv_w1<<<(512 * 2112 + 255) / 256, 256, 0, stream>>>(l1_Wih, W1hi, W1lo, 512 * 2112);

  for (int c = 0; c < N_CHUNKS; ++c) {
    int g0 = c * CHUNK_G;
    gat1_kernel<<<CHUNK_G, 256, 0, stream>>>(x, src, dst, eattr, g1_Wl, g1_Wr, g1_We,
                                             g1_att, g1_b, h1hi, h1lo, g0);
    // 64x64 tiles, BK=64 (2 panels/barrier): grid (16, 132) = 2112 blocks
    dim3 grid(1024 / 64, CHUNK_N / 64);
    gemm_mfma<2, 2><<<grid, 256, 0, stream>>>(h1hi, h1lo, B2hi, B2lo, xlr2c,
                                              (const float*)nullptr, (const float*)nullptr,
                                              CHUNK_N, 1024, HC);
    gat2_kernel<<<CHUNK_G, 256, 0, stream>>>(xlr2c, src, dst, eattr, g2_We,
                                             g2_att, g2_b, h2hi, h2lo, g0);
  }

  {
    dim3 grid(512 / 64, G_GRAPHS / 64);
    gemm_mfma<2, 2><<<grid, 256, 0, stream>>>(h2hi, h2lo, W1hi, W1lo, X1,
                                              l1_bih, l1_bhh,
                                              G_GRAPHS, 512, N_NODES * HID);
  }

  lstm1_kernel<<<BATCH, 1024, 0, stream>>>(X1, l1_Whh, Y1);
  x2_kernel<<<G_GRAPHS, 256, 0, stream>>>(Y1, l2_Wih, l2_bih, l2_bhh, X2);
  lstm2_fc_kernel<<<BATCH, 256, 0, stream>>>(X2, l2_Whh, fc_W, fc_b, out);
}

// Round 8
// 661.131 us; speedup vs baseline: 2.1436x; 1.2162x over previous
//
#include <hip/hip_runtime.h>
#include <math.h>

// ---- problem constants ----
#define N_NODES 33
#define SEQ 24
#define BATCH 64
#define G_GRAPHS (BATCH * SEQ)          // 1536
#define EPG 64
#define E_EDGES (G_GRAPHS * EPG)        // 98304
#define N_TOTAL (G_GRAPHS * N_NODES)    // 50688
#define HID 64
#define HEADS 8
#define HC (HID * HEADS)                // 512
#define LSTM1_H 128
#define LSTM2_H 64
#define NEG_SLOPE 0.2f

__device__ __forceinline__ float sigmoidf_(float x) { return 1.f / (1.f + expf(-x)); }
__device__ __forceinline__ float eluf_(float x) { return x > 0.f ? x : expm1f(x); }
__device__ __forceinline__ float lreluf_(float x) { return x > 0.f ? x : NEG_SLOPE * x; }

// bf16 (RNE) pack/unpack on raw shorts
__device__ __forceinline__ short f2bf(float x) {
  unsigned u = __float_as_uint(x);
  unsigned r = (u + 0x7fffu + ((u >> 16) & 1u)) >> 16;
  return (short)r;
}
__device__ __forceinline__ float bf2f(short b) {
  return __uint_as_float(((unsigned)(unsigned short)b) << 16);
}

typedef __attribute__((ext_vector_type(8))) short bf16x8;
typedef __attribute__((ext_vector_type(4))) float f32x4;

__device__ __forceinline__ void gl2lds16(const void* g, void* l) {
  __builtin_amdgcn_global_load_lds(
      (__attribute__((address_space(1))) const unsigned int*)g,
      (__attribute__((address_space(3))) unsigned int*)l, 16, 0, 0);
}

// ============================================================
// GAT layer 1 (round-4 version — conflict-free, verified)
// ============================================================
__global__ __launch_bounds__(256) void gat1_kernel(
    const float* __restrict__ x, const int* __restrict__ src, const int* __restrict__ dst,
    const float* __restrict__ ea, const float* __restrict__ Wl, const float* __restrict__ Wr,
    const float* __restrict__ We, const float* __restrict__ att, const float* __restrict__ bias,
    short* __restrict__ h1hi, short* __restrict__ h1lo, int g0) {
  __shared__ alignas(16) float Wl_s[2 * 512];
  __shared__ alignas(16) float Wr_s[2 * 512];
  __shared__ alignas(16) float We_s[3 * 512];
  __shared__ alignas(16) float att_s[512];
  __shared__ float xs0_s[N_NODES + 1], xs1_s[N_NODES + 1];
  __shared__ float easX[EPG], easY[EPG], easZ[EPG];
  __shared__ float logit_s[HEADS * 65];   // padded stride 65
  __shared__ int sloc[EPG], dloc[EPG], deg[N_NODES], start[N_NODES], fill[N_NODES], elist[EPG];

  const int g = g0 + blockIdx.x, tid = threadIdx.x;
  const int nb = g * N_NODES, eb = g * EPG;
  const int lb = blockIdx.x * N_NODES;

  for (int i = tid; i < 1024; i += 256) { Wl_s[i] = Wl[i]; Wr_s[i] = Wr[i]; }
  for (int i = tid; i < 1536; i += 256) We_s[i] = We[i];
  for (int i = tid; i < 512; i += 256) att_s[i] = att[i];
  if (tid < 2 * N_NODES) {
    float v = x[nb * 2 + tid];
    if (tid & 1) xs1_s[tid >> 1] = v; else xs0_s[tid >> 1] = v;
  }
  if (tid < EPG) {
    easX[tid] = ea[(eb + tid) * 3 + 0];
    easY[tid] = ea[(eb + tid) * 3 + 1];
    easZ[tid] = ea[(eb + tid) * 3 + 2];
    sloc[tid] = src[eb + tid] - nb;
    dloc[tid] = dst[eb + tid] - nb;
  }
  if (tid < N_NODES) { deg[tid] = 0; fill[tid] = 0; }
  __syncthreads();
  if (tid < EPG) atomicAdd(&deg[dloc[tid]], 1);
  __syncthreads();
  if (tid == 0) { int a = 0; for (int n = 0; n < N_NODES; ++n) { start[n] = a; a += deg[n]; } }
  __syncthreads();
  if (tid < EPG) { int d = dloc[tid]; int p = atomicAdd(&fill[d], 1); elist[start[d] + p] = tid; }

  // logits: h = t>>6 (wave-uniform), e = t&63 (= lane). Weight reads broadcast.
  for (int t = tid; t < EPG * HEADS; t += 256) {
    int h = t >> 6, e = t & 63;
    int s = sloc[e], d = dloc[e];
    float xs0 = xs0_s[s], xs1 = xs1_s[s], xd0 = xs0_s[d], xd1 = xs1_s[d];
    float e0 = easX[e], e1 = easY[e], e2 = easZ[e];
    float acc = 0.f;
    int base = h * 64;
    #pragma unroll
    for (int c4 = 0; c4 < 16; ++c4) {
      int j = base + c4 * 4;
      f32x4 wl0 = *(const f32x4*)(Wl_s + j);
      f32x4 wl1 = *(const f32x4*)(Wl_s + 512 + j);
      f32x4 wr0 = *(const f32x4*)(Wr_s + j);
      f32x4 wr1 = *(const f32x4*)(Wr_s + 512 + j);
      f32x4 we0 = *(const f32x4*)(We_s + j);
      f32x4 we1 = *(const f32x4*)(We_s + 512 + j);
      f32x4 we2 = *(const f32x4*)(We_s + 1024 + j);
      f32x4 at  = *(const f32x4*)(att_s + j);
      #pragma unroll
      for (int q = 0; q < 4; ++q) {
        float v = xs0 * wl0[q] + xs1 * wl1[q]
                + xd0 * wr0[q] + xd1 * wr1[q]
                + e0 * we0[q] + e1 * we1[q] + e2 * we2[q];
        acc += lreluf_(v) * at[q];
      }
    }
    logit_s[h * 65 + e] = acc;
  }
  __syncthreads();

  // segment softmax: h = t>>6 (uniform), n = t&63 (lane), skip n>=33
  for (int t = tid; t < HEADS * 64; t += 256) {
    int h = t >> 6, n = t & 63;
    if (n < N_NODES) {
      int s0 = start[n], dn = deg[n];
      float mx = -1e30f;
      for (int i = 0; i < dn; ++i) mx = fmaxf(mx, logit_s[h * 65 + elist[s0 + i]]);
      float den = 0.f;
      for (int i = 0; i < dn; ++i) den += expf(logit_s[h * 65 + elist[s0 + i]] - mx);
      float inv = 1.f / (den + 1e-16f);
      for (int i = 0; i < dn; ++i) {
        int e = elist[s0 + i];
        logit_s[h * 65 + e] = expf(logit_s[h * 65 + e] - mx) * inv;
      }
    }
  }
  __syncthreads();

  // aggregation: task = (n, 8-channel block). n = t>>6 wave-uniform, jb = lane.
  for (int t = tid; t < N_NODES * 64; t += 256) {
    int n = t >> 6, jb = t & 63;
    int j0 = jb * 8, h = jb >> 3;
    f32x4 wa0 = *(const f32x4*)(Wl_s + j0);
    f32x4 wa1 = *(const f32x4*)(Wl_s + j0 + 4);
    f32x4 wb0 = *(const f32x4*)(Wl_s + 512 + j0);
    f32x4 wb1 = *(const f32x4*)(Wl_s + 512 + j0 + 4);
    float acc[8] = {};
    int s0 = start[n], dn = deg[n];
    for (int i = 0; i < dn; ++i) {
      int e = elist[s0 + i]; int s = sloc[e];
      float a = logit_s[h * 65 + e];
      float ax0 = a * xs0_s[s], ax1 = a * xs1_s[s];
      #pragma unroll
      for (int q = 0; q < 4; ++q) {
        acc[q]     += ax0 * wa0[q] + ax1 * wb0[q];
        acc[4 + q] += ax0 * wa1[q] + ax1 * wb1[q];
      }
    }
    f32x4 b0 = *(const f32x4*)(bias + j0);
    f32x4 b1 = *(const f32x4*)(bias + j0 + 4);
    bf16x8 vh, vl;
    #pragma unroll
    for (int cc = 0; cc < 8; ++cc) {
      float bb = (cc < 4) ? b0[cc] : b1[cc - 4];
      float v = eluf_(acc[cc] + bb);
      short hb = f2bf(v);
      vh[cc] = hb;
      vl[cc] = f2bf(v - bf2f(hb));
    }
    size_t o = (size_t)(lb + n) * HC + j0;
    *(bf16x8*)(h1hi + o) = vh;
    *(bf16x8*)(h1lo + o) = vl;
  }
}

// ============================================================
// weight conversion kernels (unchanged)
// ============================================================
__global__ __launch_bounds__(256) void conv_g2w(
    const float* __restrict__ Wl, const float* __restrict__ Wr,
    short* __restrict__ Bhi, short* __restrict__ Blo) {
  int idx = blockIdx.x * 256 + threadIdx.x;
  int n = idx >> 9, k = idx & 511;
  float v = (n < 512) ? Wl[k * 512 + n] : Wr[k * 512 + (n - 512)];
  short hi = f2bf(v);
  Bhi[idx] = hi;
  Blo[idx] = f2bf(v - bf2f(hi));
}

__global__ __launch_bounds__(256) void conv_w1(
    const float* __restrict__ W, short* __restrict__ Whi, short* __restrict__ Wlo, int total) {
  int idx = blockIdx.x * 256 + threadIdx.x;
  if (idx >= total) return;
  float v = W[idx];
  short hi = f2bf(v);
  Whi[idx] = hi;
  Wlo[idx] = f2bf(v - bf2f(hi));
}

// ============================================================
// split-bf16 MFMA GEMM, BK=64 (two 32-panels/barrier), 64x64 tiles,
// XCD-aware 1D grid swizzle:
//   b -> xcd = b&7, q = b>>3, c = q % NT, rg = q / NT, r = rg*8 + xcd
// All blocks of row-stripe r%8==xcd land on one XCD; its columns iterate
// fastest, so each A-tile is fetched by exactly one XCD's L2 and reused
// across all NT column tiles. (Round-7 counters: FETCH 68.8 MB vs ideal
// 19.4 — cross-XCD A re-fetch. XCD=b%8 is a perf heuristic only; any
// mapping is correct.)
// strideA/strideB decouple row stride from K extent (for split-K).
// K % 64 == 0 required.
// ROUND-6 LESSON: do NOT stream an MFMA operand global->VGPR (144 us,
// MfmaUtil 7% — scattered 64B segments, latency-serialized).
// ============================================================
__global__ __launch_bounds__(256) void gemm_mfma(
    const short* __restrict__ Ahi, const short* __restrict__ Alo,
    const short* __restrict__ Bhi, const short* __restrict__ Blo,
    float* __restrict__ C, const float* __restrict__ bias1, const float* __restrict__ bias2,
    int M, int N, int K, int strideA, int strideB) {
  constexpr int BM = 64, BN = 64;
  __shared__ short lds[(BM + BN) * 2 * 64];
  short* Ah_s = lds;                    // [2][BM][32]
  short* Al_s = Ah_s + BM * 64;
  short* Bh_s = Al_s + BM * 64;         // [2][BN][32]
  short* Bl_s = Bh_s + BN * 64;

  const int R = M >> 6, NT = N >> 6;
  int b = blockIdx.x;
  int xcd = b & 7, q = b >> 3;
  int ct = q % NT, rg = q / NT;
  int r = rg * 8 + xcd;
  if (r >= R) return;

  const int tid = threadIdx.x;
  const int wave = tid >> 6, lane = tid & 63;
  const int wm = wave >> 1, wn = wave & 1;
  const int bm = r * BM, bn = ct * BN;

  const int rA = lane >> 2;          // 0..15
  const int cA = (lane & 3) * 8;     // 16B unit within 32-k panel row

  f32x4 acc[2][2];
  #pragma unroll
  for (int tm = 0; tm < 2; ++tm)
    #pragma unroll
    for (int tn = 0; tn < 2; ++tn) acc[tm][tn] = {0.f, 0.f, 0.f, 0.f};

  for (int k0 = 0; k0 < K; k0 += 64) {
    #pragma unroll
    for (int p = 0; p < 2; ++p) {
      int kk = k0 + p * 32;
      {
        int row = wave * 16;
        size_t go = (size_t)(bm + row + rA) * strideA + kk + cA;
        int lo = p * BM * 32 + row * 32;
        gl2lds16(Ahi + go, Ah_s + lo);
        gl2lds16(Alo + go, Al_s + lo);
      }
      {
        int row = wave * 16;
        size_t go = (size_t)(bn + row + rA) * strideB + kk + cA;
        int lo = p * BN * 32 + row * 32;
        gl2lds16(Bhi + go, Bh_s + lo);
        gl2lds16(Blo + go, Bl_s + lo);
      }
    }
    __syncthreads();

    const int fr = lane & 15;
    const int fk = (lane >> 4) * 8;
    #pragma unroll
    for (int p = 0; p < 2; ++p) {
      const int pA = p * BM * 32, pB = p * BN * 32;
      bf16x8 a_h[2], a_l[2], b_h[2], b_l[2];
      #pragma unroll
      for (int tm = 0; tm < 2; ++tm) {
        int rr = (wm * 2 + tm) * 16 + fr;
        a_h[tm] = *(const bf16x8*)(Ah_s + pA + rr * 32 + fk);
        a_l[tm] = *(const bf16x8*)(Al_s + pA + rr * 32 + fk);
      }
      #pragma unroll
      for (int tn = 0; tn < 2; ++tn) {
        int rr = (wn * 2 + tn) * 16 + fr;
        b_h[tn] = *(const bf16x8*)(Bh_s + pB + rr * 32 + fk);
        b_l[tn] = *(const bf16x8*)(Bl_s + pB + rr * 32 + fk);
      }
      #pragma unroll
      for (int tm = 0; tm < 2; ++tm)
        #pragma unroll
        for (int tn = 0; tn < 2; ++tn) {
          acc[tm][tn] = __builtin_amdgcn_mfma_f32_16x16x32_bf16(a_h[tm], b_h[tn], acc[tm][tn], 0, 0, 0);
          acc[tm][tn] = __builtin_amdgcn_mfma_f32_16x16x32_bf16(a_h[tm], b_l[tn], acc[tm][tn], 0, 0, 0);
          acc[tm][tn] = __builtin_amdgcn_mfma_f32_16x16x32_bf16(a_l[tm], b_h[tn], acc[tm][tn], 0, 0, 0);
        }
    }
    __syncthreads();
  }

  // epilogue: C/D layout col=lane&15, row=(lane>>4)*4+reg  [m89/m91 verified]
  const int col0 = lane & 15, rq = (lane >> 4) * 4;
  #pragma unroll
  for (int tm = 0; tm < 2; ++tm)
    #pragma unroll
    for (int tn = 0; tn < 2; ++tn) {
      int col = bn + (wn * 2 + tn) * 16 + col0;
      float badd = 0.f;
      if (bias1) badd += bias1[col];
      if (bias2) badd += bias2[col];
      #pragma unroll
      for (int rr = 0; rr < 4; ++rr) {
        int row = bm + (wm * 2 + tm) * 16 + rq + rr;
        C[(size_t)row * N + col] = acc[tm][tn][rr] + badd;
      }
    }
}

// ============================================================
// GAT layer 2 (round-4 version — verified)
// ============================================================
__global__ __launch_bounds__(256) void gat2_kernel(
    const float* __restrict__ xlr, const int* __restrict__ src, const int* __restrict__ dst,
    const float* __restrict__ ea, const float* __restrict__ We,
    const float* __restrict__ att, const float* __restrict__ bias,
    short* __restrict__ h2hi, short* __restrict__ h2lo, int g0) {
  __shared__ float xl_s[512 * N_NODES];   // [j][s]
  __shared__ float xr_s[512 * N_NODES];   // [j][d]
  __shared__ alignas(16) float We_s[3 * 512];
  __shared__ alignas(16) float att_s[512];
  __shared__ float b_s[HID];
  __shared__ float easX[EPG], easY[EPG], easZ[EPG];
  __shared__ float logit_s[HEADS * 65];
  __shared__ int sloc[EPG], dloc[EPG], deg[N_NODES], start[N_NODES], fill[N_NODES], elist[EPG];

  const int g = g0 + blockIdx.x, tid = threadIdx.x;
  const int nb = g * N_NODES, eb = g * EPG;
  const int lb = blockIdx.x * N_NODES;

  for (int i = tid; i < 1536; i += 256) We_s[i] = We[i];
  for (int i = tid; i < 512; i += 256) att_s[i] = att[i];
  if (tid < HID) b_s[tid] = bias[tid];
  for (int i = tid; i < N_NODES * 1024; i += 256) {
    int s = i >> 10, j = i & 1023;
    float v = xlr[(size_t)(lb + s) * 1024 + j];
    if (j < 512) xl_s[j * N_NODES + s] = v;
    else         xr_s[(j - 512) * N_NODES + s] = v;
  }
  if (tid < EPG) {
    easX[tid] = ea[(eb + tid) * 3 + 0];
    easY[tid] = ea[(eb + tid) * 3 + 1];
    easZ[tid] = ea[(eb + tid) * 3 + 2];
    sloc[tid] = src[eb + tid] - nb;
    dloc[tid] = dst[eb + tid] - nb;
  }
  if (tid < N_NODES) { deg[tid] = 0; fill[tid] = 0; }
  __syncthreads();
  if (tid < EPG) atomicAdd(&deg[dloc[tid]], 1);
  __syncthreads();
  if (tid == 0) { int a = 0; for (int n = 0; n < N_NODES; ++n) { start[n] = a; a += deg[n]; } }
  __syncthreads();
  if (tid < EPG) { int d = dloc[tid]; int p = atomicAdd(&fill[d], 1); elist[start[d] + p] = tid; }

  for (int t = tid; t < EPG * HEADS; t += 256) {
    int h = t >> 6, e = t & 63;
    int s = sloc[e], d = dloc[e];
    float e0 = easX[e], e1 = easY[e], e2 = easZ[e];
    float acc = 0.f;
    int base = h * 64;
    #pragma unroll
    for (int c4 = 0; c4 < 16; ++c4) {
      int j = base + c4 * 4;
      f32x4 we0 = *(const f32x4*)(We_s + j);
      f32x4 we1 = *(const f32x4*)(We_s + 512 + j);
      f32x4 we2 = *(const f32x4*)(We_s + 1024 + j);
      f32x4 at  = *(const f32x4*)(att_s + j);
      #pragma unroll
      for (int q = 0; q < 4; ++q) {
        int jj = j + q;
        float v = xl_s[jj * N_NODES + s] + xr_s[jj * N_NODES + d]
                + e0 * we0[q] + e1 * we1[q] + e2 * we2[q];
        acc += lreluf_(v) * at[q];
      }
    }
    logit_s[h * 65 + e] = acc;
  }
  __syncthreads();

  for (int t = tid; t < HEADS * 64; t += 256) {
    int h = t >> 6, n = t & 63;
    if (n < N_NODES) {
      int s0 = start[n], dn = deg[n];
      float mx = -1e30f;
      for (int i = 0; i < dn; ++i) mx = fmaxf(mx, logit_s[h * 65 + elist[s0 + i]]);
      float den = 0.f;
      for (int i = 0; i < dn; ++i) den += expf(logit_s[h * 65 + elist[s0 + i]] - mx);
      float inv = 1.f / (den + 1e-16f);
      for (int i = 0; i < dn; ++i) {
        int e = elist[s0 + i];
        logit_s[h * 65 + e] = expf(logit_s[h * 65 + e] - mx) * inv;
      }
    }
  }
  __syncthreads();

  for (int t = tid; t < N_NODES * 8; t += 256) {
    int n = t >> 3, jb = t & 7;
    int j0 = jb * 8;
    float acc[8] = {};
    int s0 = start[n], dn = deg[n];
    for (int i = 0; i < dn; ++i) {
      int e = elist[s0 + i]; int s = sloc[e];
      float al[8];
      #pragma unroll
      for (int h = 0; h < 8; ++h) al[h] = logit_s[h * 65 + e];
      #pragma unroll
      for (int cc = 0; cc < 8; ++cc) {
        int c = j0 + cc;
        float sum = 0.f;
        #pragma unroll
        for (int h = 0; h < 8; ++h) sum += al[h] * xl_s[(h * 64 + c) * N_NODES + s];
        acc[cc] += sum;
      }
    }
    bf16x8 vh, vl;
    #pragma unroll
    for (int cc = 0; cc < 8; ++cc) {
      float v = eluf_(acc[cc] * 0.125f + b_s[j0 + cc]);
      short hb = f2bf(v);
      vh[cc] = hb;
      vl[cc] = f2bf(v - bf2f(hb));
    }
    size_t o = (size_t)(nb + n) * HID + j0;
    *(bf16x8*)(h2hi + o) = vh;
    *(bf16x8*)(h2lo + o) = vl;
  }
}

// ============================================================
// LSTM1 (round-5 no-spill version); X = X1a + X1b (split-K final GEMM)
// ============================================================
__global__ __launch_bounds__(1024, 4) void lstm1_kernel(
    const float* __restrict__ Xa, const float* __restrict__ Xb,
    const float* __restrict__ Whh, float* __restrict__ Y) {
  __shared__ float hs[LSTM1_H], cs[LSTM1_H], part[4 * LSTM1_H], gs[4 * LSTM1_H];
  const int tid = threadIdx.x;
  const int j = tid & 511, half = tid >> 9;
  const int b = blockIdx.x;
  float4 w[16];
  const float4* wp = (const float4*)(Whh + (size_t)j * LSTM1_H + half * 64);
  #pragma unroll
  for (int q = 0; q < 16; ++q) w[q] = wp[q];
  if (tid < LSTM1_H) { hs[tid] = 0.f; cs[tid] = 0.f; }
  __syncthreads();
  for (int t = 0; t < SEQ; ++t) {
    const float* hb = hs + half * 64;
    float acc = 0.f;
    #pragma unroll
    for (int q = 0; q < 16; ++q) {
      acc += w[q].x * hb[4 * q] + w[q].y * hb[4 * q + 1]
           + w[q].z * hb[4 * q + 2] + w[q].w * hb[4 * q + 3];
    }
    if (half) part[j] = acc;
    __syncthreads();
    if (!half) {
      size_t xo = ((size_t)b * SEQ + t) * 512 + j;
      gs[j] = acc + part[j] + Xa[xo] + Xb[xo];
    }
    __syncthreads();
    if (tid < LSTM1_H) {
      float ig = sigmoidf_(gs[tid]);
      float fg = sigmoidf_(gs[LSTM1_H + tid]);
      float gg = tanhf(gs[2 * LSTM1_H + tid]);
      float og = sigmoidf_(gs[3 * LSTM1_H + tid]);
      float c = fg * cs[tid] + ig * gg;
      cs[tid] = c;
      float h = og * tanhf(c);
      hs[tid] = h;
      Y[((size_t)b * SEQ + t) * LSTM1_H + tid] = h;
    }
    __syncthreads();
  }
}

__global__ __launch_bounds__(256) void x2_kernel(
    const float* __restrict__ Y1, const float* __restrict__ Wih,
    const float* __restrict__ bih, const float* __restrict__ bhh,
    float* __restrict__ X2) {
  __shared__ float ys[LSTM1_H];
  const int g = blockIdx.x, j = threadIdx.x;
  if (j < LSTM1_H) ys[j] = Y1[(size_t)g * LSTM1_H + j];
  __syncthreads();
  const float4* wp = (const float4*)(Wih + (size_t)j * LSTM1_H);
  float acc = bih[j] + bhh[j];
  #pragma unroll
  for (int q = 0; q < 32; ++q) {
    float4 w = wp[q];
    acc += w.x * ys[4 * q] + w.y * ys[4 * q + 1] + w.z * ys[4 * q + 2] + w.w * ys[4 * q + 3];
  }
  X2[(size_t)g * 256 + j] = acc;
}

__global__ __launch_bounds__(256, 2) void lstm2_fc_kernel(
    const float* __restrict__ X, const float* __restrict__ Whh,
    const float* __restrict__ fcW, const float* __restrict__ fcb,
    float* __restrict__ out) {
  __shared__ float hs[LSTM2_H], cs[LSTM2_H], gs[4 * LSTM2_H];
  const int b = blockIdx.x, j = threadIdx.x;
  float4 w[16];
  const float4* wp = (const float4*)(Whh + (size_t)j * LSTM2_H);
  #pragma unroll
  for (int q = 0; q < 16; ++q) w[q] = wp[q];
  if (j < LSTM2_H) { hs[j] = 0.f; cs[j] = 0.f; }
  __syncthreads();
  for (int t = 0; t < SEQ; ++t) {
    float acc = X[((size_t)b * SEQ + t) * 256 + j];
    #pragma unroll
    for (int q = 0; q < 16; ++q) {
      acc += w[q].x * hs[4 * q] + w[q].y * hs[4 * q + 1]
           + w[q].z * hs[4 * q + 2] + w[q].w * hs[4 * q + 3];
    }
    gs[j] = acc;
    __syncthreads();
    if (j < LSTM2_H) {
      float ig = sigmoidf_(gs[j]);
      float fg = sigmoidf_(gs[LSTM2_H + j]);
      float gg = tanhf(gs[2 * LSTM2_H + j]);
      float og = sigmoidf_(gs[3 * LSTM2_H + j]);
      float c = fg * cs[j] + ig * gg;
      cs[j] = c;
      hs[j] = og * tanhf(c);
    }
    __syncthreads();
  }
  if (j < 4) {
    float acc = fcb[j];
    #pragma unroll
    for (int k = 0; k < LSTM2_H; ++k) acc += fcW[j * LSTM2_H + k] * hs[k];
    out[b * 4 + j] = acc;
  }
}

// ============================================================
extern "C" void kernel_launch(void* const* d_in, const int* in_sizes, int n_in,
                              void* d_out, int out_size, void* d_ws, size_t ws_size,
                              hipStream_t stream) {
  const float* x       = (const float*)d_in[0];
  const int*   eidx    = (const int*)d_in[1];
  const float* eattr   = (const float*)d_in[2];
  const float* g1_Wl   = (const float*)d_in[3];
  const float* g1_Wr   = (const float*)d_in[4];
  const float* g1_We   = (const float*)d_in[5];
  const float* g1_att  = (const float*)d_in[6];
  const float* g1_b    = (const float*)d_in[7];
  const float* g2_Wl   = (const float*)d_in[8];
  const float* g2_Wr   = (const float*)d_in[9];
  const float* g2_We   = (const float*)d_in[10];
  const float* g2_att  = (const float*)d_in[11];
  const float* g2_b    = (const float*)d_in[12];
  const float* l1_Wih  = (const float*)d_in[13];
  const float* l1_Whh  = (const float*)d_in[14];
  const float* l1_bih  = (const float*)d_in[15];
  const float* l1_bhh  = (const float*)d_in[16];
  const float* l2_Wih  = (const float*)d_in[17];
  const float* l2_Whh  = (const float*)d_in[18];
  const float* l2_bih  = (const float*)d_in[19];
  const float* l2_bhh  = (const float*)d_in[20];
  const float* fc_W    = (const float*)d_in[21];
  const float* fc_b    = (const float*)d_in[22];
  float* out = (float*)d_out;

  const int* src = eidx;
  const int* dst = eidx + E_EDGES;

  // ---- runtime-adaptive chunking: largest chunk size whose ws layout fits.
  // ws_size is constant across calls -> same branch every call (graph-safe).
  const int cand[5] = {1, 2, 3, 4, 6};
  int nchunks = 0;
  short *h1hi = nullptr, *h1lo = nullptr, *h2hi = nullptr, *h2lo = nullptr;
  short *B2hi = nullptr, *B2lo = nullptr, *W1hi = nullptr, *W1lo = nullptr;
  float *xlr2c = nullptr, *X1a = nullptr, *X1b = nullptr, *Y1 = nullptr, *X2 = nullptr;
  int chunk_g = 0, chunk_n = 0;
  for (int ci = 0; ci < 5; ++ci) {
    int C = cand[ci];
    int CG = G_GRAPHS / C, CN = CG * N_NODES;
    char* p = (char*)d_ws;
    auto alloc = [&](size_t bytes) { char* r = p; p += (bytes + 255) & ~(size_t)255; return r; };
    short* t_h1hi  = (short*)alloc((size_t)CN * HC * 2);
    short* t_h1lo  = (short*)alloc((size_t)CN * HC * 2);
    float* t_xlr2c = (float*)alloc((size_t)CN * 1024 * 4);
    short* t_h2hi  = (short*)alloc((size_t)G_GRAPHS * 2112 * 2);
    short* t_h2lo  = (short*)alloc((size_t)G_GRAPHS * 2112 * 2);
    short* t_B2hi  = (short*)alloc((size_t)1024 * 512 * 2);
    short* t_B2lo  = (short*)alloc((size_t)1024 * 512 * 2);
    short* t_W1hi  = (short*)alloc((size_t)512 * 2112 * 2);
    short* t_W1lo  = (short*)alloc((size_t)512 * 2112 * 2);
    float* t_X1a   = (float*)alloc((size_t)G_GRAPHS * 512 * 4);
    float* t_X1b   = (float*)alloc((size_t)G_GRAPHS * 512 * 4);
    float* t_Y1    = (float*)alloc((size_t)G_GRAPHS * LSTM1_H * 4);
    float* t_X2    = (float*)alloc((size_t)G_GRAPHS * 256 * 4);
    if ((size_t)(p - (char*)d_ws) <= ws_size) {
      nchunks = C; chunk_g = CG; chunk_n = CN;
      h1hi = t_h1hi; h1lo = t_h1lo; xlr2c = t_xlr2c;
      h2hi = t_h2hi; h2lo = t_h2lo; B2hi = t_B2hi; B2lo = t_B2lo;
      W1hi = t_W1hi; W1lo = t_W1lo; X1a = t_X1a; X1b = t_X1b; Y1 = t_Y1; X2 = t_X2;
      break;
    }
  }
  if (nchunks == 0) return;   // guard: zero output instead of memory fault

  conv_g2w<<<(1024 * 512) / 256, 256, 0, stream>>>(g2_Wl, g2_Wr, B2hi, B2lo);
  conv_w1<<<(512 * 2112 + 255) / 256, 256, 0, stream>>>(l1_Wih, W1hi, W1lo, 512 * 2112);

  for (int c = 0; c < nchunks; ++c) {
    int g0 = c * chunk_g;
    gat1_kernel<<<chunk_g, 256, 0, stream>>>(x, src, dst, eattr, g1_Wl, g1_Wr, g1_We,
                                             g1_att, g1_b, h1hi, h1lo, g0);
    // XCD-swizzled 1D grid: 8 * ceil(R/8) * NT blocks
    int R = chunk_n / 64, NT = 1024 / 64;
    int gblocks = 8 * ((R + 7) / 8) * NT;
    gemm_mfma<<<gblocks, 256, 0, stream>>>(h1hi, h1lo, B2hi, B2lo, xlr2c,
                                           (const float*)nullptr, (const float*)nullptr,
                                           chunk_n, 1024, HC, HC, HC);
    gat2_kernel<<<chunk_g, 256, 0, stream>>>(xlr2c, src, dst, eattr, g2_We,
                                             g2_att, g2_b, h2hi, h2lo, g0);
  }

  // X1 = h2 @ l1_Wih^T + biases, split-K: 2112 = 1088 + 1024
  {
    int R = G_GRAPHS / 64, NT = 512 / 64;
    int gblocks = 8 * ((R + 7) / 8) * NT;
    gemm_mfma<<<gblocks, 256, 0, stream>>>(h2hi, h2lo, W1hi, W1lo, X1a,
                                           l1_bih, l1_bhh,
                                           G_GRAPHS, 512, 1088, 2112, 2112);
    gemm_mfma<<<gblocks, 256, 0, stream>>>(h2hi + 1088, h2lo + 1088,
                                           W1hi + 1088, W1lo + 1088, X1b,
                                           (const float*)nullptr, (const float*)nullptr,
                                           G_GRAPHS, 512, 1024, 2112, 2112);
  }

  lstm1_kernel<<<BATCH, 1024, 0, stream>>>(X1a, X1b, l1_Whh, Y1);
  x2_kernel<<<G_GRAPHS, 256, 0, stream>>>(Y1, l2_Wih, l2_bih, l2_bhh, X2);
  lstm2_fc_kernel<<<BATCH, 256, 0, stream>>>(X2, l2_Whh, fc_W, fc_b, out);
}

// Round 9
// 644.737 us; speedup vs baseline: 2.1981x; 1.0254x over previous
//
#include <hip/hip_runtime.h>
#include <math.h>

// ---- problem constants ----
#define N_NODES 33
#define SEQ 24
#define BATCH 64
#define G_GRAPHS (BATCH * SEQ)          // 1536
#define EPG 64
#define E_EDGES (G_GRAPHS * EPG)        // 98304
#define N_TOTAL (G_GRAPHS * N_NODES)    // 50688
#define HID 64
#define HEADS 8
#define HC (HID * HEADS)                // 512
#define LSTM1_H 128
#define LSTM2_H 64
#define NEG_SLOPE 0.2f

__device__ __forceinline__ float sigmoidf_(float x) { return 1.f / (1.f + expf(-x)); }
__device__ __forceinline__ float eluf_(float x) { return x > 0.f ? x : expm1f(x); }
__device__ __forceinline__ float lreluf_(float x) { return x > 0.f ? x : NEG_SLOPE * x; }

// bf16 (RNE) pack/unpack on raw shorts
__device__ __forceinline__ short f2bf(float x) {
  unsigned u = __float_as_uint(x);
  unsigned r = (u + 0x7fffu + ((u >> 16) & 1u)) >> 16;
  return (short)r;
}
__device__ __forceinline__ float bf2f(short b) {
  return __uint_as_float(((unsigned)(unsigned short)b) << 16);
}

typedef __attribute__((ext_vector_type(8))) short bf16x8;
typedef __attribute__((ext_vector_type(4))) float f32x4;

__device__ __forceinline__ void gl2lds16(const void* g, void* l) {
  __builtin_amdgcn_global_load_lds(
      (__attribute__((address_space(1))) const unsigned int*)g,
      (__attribute__((address_space(3))) unsigned int*)l, 16, 0, 0);
}

// ============================================================
// GAT layer 1 (round-4 version — conflict-free, verified)
// ============================================================
__global__ __launch_bounds__(256) void gat1_kernel(
    const float* __restrict__ x, const int* __restrict__ src, const int* __restrict__ dst,
    const float* __restrict__ ea, const float* __restrict__ Wl, const float* __restrict__ Wr,
    const float* __restrict__ We, const float* __restrict__ att, const float* __restrict__ bias,
    short* __restrict__ h1hi, short* __restrict__ h1lo, int g0) {
  __shared__ alignas(16) float Wl_s[2 * 512];
  __shared__ alignas(16) float Wr_s[2 * 512];
  __shared__ alignas(16) float We_s[3 * 512];
  __shared__ alignas(16) float att_s[512];
  __shared__ float xs0_s[N_NODES + 1], xs1_s[N_NODES + 1];
  __shared__ float easX[EPG], easY[EPG], easZ[EPG];
  __shared__ float logit_s[HEADS * 65];   // padded stride 65
  __shared__ int sloc[EPG], dloc[EPG], deg[N_NODES], start[N_NODES], fill[N_NODES], elist[EPG];

  const int g = g0 + blockIdx.x, tid = threadIdx.x;
  const int nb = g * N_NODES, eb = g * EPG;
  const int lb = blockIdx.x * N_NODES;

  for (int i = tid; i < 1024; i += 256) { Wl_s[i] = Wl[i]; Wr_s[i] = Wr[i]; }
  for (int i = tid; i < 1536; i += 256) We_s[i] = We[i];
  for (int i = tid; i < 512; i += 256) att_s[i] = att[i];
  if (tid < 2 * N_NODES) {
    float v = x[nb * 2 + tid];
    if (tid & 1) xs1_s[tid >> 1] = v; else xs0_s[tid >> 1] = v;
  }
  if (tid < EPG) {
    easX[tid] = ea[(eb + tid) * 3 + 0];
    easY[tid] = ea[(eb + tid) * 3 + 1];
    easZ[tid] = ea[(eb + tid) * 3 + 2];
    sloc[tid] = src[eb + tid] - nb;
    dloc[tid] = dst[eb + tid] - nb;
  }
  if (tid < N_NODES) { deg[tid] = 0; fill[tid] = 0; }
  __syncthreads();
  if (tid < EPG) atomicAdd(&deg[dloc[tid]], 1);
  __syncthreads();
  if (tid == 0) { int a = 0; for (int n = 0; n < N_NODES; ++n) { start[n] = a; a += deg[n]; } }
  __syncthreads();
  if (tid < EPG) { int d = dloc[tid]; int p = atomicAdd(&fill[d], 1); elist[start[d] + p] = tid; }

  // logits: h = t>>6 (wave-uniform), e = t&63 (= lane). Weight reads broadcast.
  for (int t = tid; t < EPG * HEADS; t += 256) {
    int h = t >> 6, e = t & 63;
    int s = sloc[e], d = dloc[e];
    float xs0 = xs0_s[s], xs1 = xs1_s[s], xd0 = xs0_s[d], xd1 = xs1_s[d];
    float e0 = easX[e], e1 = easY[e], e2 = easZ[e];
    float acc = 0.f;
    int base = h * 64;
    #pragma unroll
    for (int c4 = 0; c4 < 16; ++c4) {
      int j = base + c4 * 4;
      f32x4 wl0 = *(const f32x4*)(Wl_s + j);
      f32x4 wl1 = *(const f32x4*)(Wl_s + 512 + j);
      f32x4 wr0 = *(const f32x4*)(Wr_s + j);
      f32x4 wr1 = *(const f32x4*)(Wr_s + 512 + j);
      f32x4 we0 = *(const f32x4*)(We_s + j);
      f32x4 we1 = *(const f32x4*)(We_s + 512 + j);
      f32x4 we2 = *(const f32x4*)(We_s + 1024 + j);
      f32x4 at  = *(const f32x4*)(att_s + j);
      #pragma unroll
      for (int q = 0; q < 4; ++q) {
        float v = xs0 * wl0[q] + xs1 * wl1[q]
                + xd0 * wr0[q] + xd1 * wr1[q]
                + e0 * we0[q] + e1 * we1[q] + e2 * we2[q];
        acc += lreluf_(v) * at[q];
      }
    }
    logit_s[h * 65 + e] = acc;
  }
  __syncthreads();

  // segment softmax: h = t>>6 (uniform), n = t&63 (lane), skip n>=33
  for (int t = tid; t < HEADS * 64; t += 256) {
    int h = t >> 6, n = t & 63;
    if (n < N_NODES) {
      int s0 = start[n], dn = deg[n];
      float mx = -1e30f;
      for (int i = 0; i < dn; ++i) mx = fmaxf(mx, logit_s[h * 65 + elist[s0 + i]]);
      float den = 0.f;
      for (int i = 0; i < dn; ++i) den += expf(logit_s[h * 65 + elist[s0 + i]] - mx);
      float inv = 1.f / (den + 1e-16f);
      for (int i = 0; i < dn; ++i) {
        int e = elist[s0 + i];
        logit_s[h * 65 + e] = expf(logit_s[h * 65 + e] - mx) * inv;
      }
    }
  }
  __syncthreads();

  // aggregation: task = (n, 8-channel block). n = t>>6 wave-uniform, jb = lane.
  for (int t = tid; t < N_NODES * 64; t += 256) {
    int n = t >> 6, jb = t & 63;
    int j0 = jb * 8, h = jb >> 3;
    f32x4 wa0 = *(const f32x4*)(Wl_s + j0);
    f32x4 wa1 = *(const f32x4*)(Wl_s + j0 + 4);
    f32x4 wb0 = *(const f32x4*)(Wl_s + 512 + j0);
    f32x4 wb1 = *(const f32x4*)(Wl_s + 512 + j0 + 4);
    float acc[8] = {};
    int s0 = start[n], dn = deg[n];
    for (int i = 0; i < dn; ++i) {
      int e = elist[s0 + i]; int s = sloc[e];
      float a = logit_s[h * 65 + e];
      float ax0 = a * xs0_s[s], ax1 = a * xs1_s[s];
      #pragma unroll
      for (int q = 0; q < 4; ++q) {
        acc[q]     += ax0 * wa0[q] + ax1 * wb0[q];
        acc[4 + q] += ax0 * wa1[q] + ax1 * wb1[q];
      }
    }
    f32x4 b0 = *(const f32x4*)(bias + j0);
    f32x4 b1 = *(const f32x4*)(bias + j0 + 4);
    bf16x8 vh, vl;
    #pragma unroll
    for (int cc = 0; cc < 8; ++cc) {
      float bb = (cc < 4) ? b0[cc] : b1[cc - 4];
      float v = eluf_(acc[cc] + bb);
      short hb = f2bf(v);
      vh[cc] = hb;
      vl[cc] = f2bf(v - bf2f(hb));
    }
    size_t o = (size_t)(lb + n) * HC + j0;
    *(bf16x8*)(h1hi + o) = vh;
    *(bf16x8*)(h1lo + o) = vl;
  }
}

// ============================================================
// merged weight conversion: blocks [0, 2048) -> g2 B-matrix transpose+split,
// blocks [2048, 6272) -> l1_Wih elementwise split.
// ============================================================
__global__ __launch_bounds__(256) void conv_all(
    const float* __restrict__ Wl, const float* __restrict__ Wr,
    short* __restrict__ Bhi, short* __restrict__ Blo,
    const float* __restrict__ W1, short* __restrict__ W1hi, short* __restrict__ W1lo) {
  int b = blockIdx.x;
  if (b < 2048) {
    int idx = b * 256 + threadIdx.x;   // n*512 + k
    int n = idx >> 9, k = idx & 511;
    float v = (n < 512) ? Wl[k * 512 + n] : Wr[k * 512 + (n - 512)];
    short hi = f2bf(v);
    Bhi[idx] = hi;
    Blo[idx] = f2bf(v - bf2f(hi));
  } else {
    int idx = (b - 2048) * 256 + threadIdx.x;
    if (idx < 512 * 2112) {
      float v = W1[idx];
      short hi = f2bf(v);
      W1hi[idx] = hi;
      W1lo[idx] = f2bf(v - bf2f(hi));
    }
  }
}

// ============================================================
// split-bf16 MFMA GEMM, templated tile:
//   WM,WN = MFMA 16x16 subtiles per wave per dim (2x2 wave grid)
//   NP    = number of 32-wide K panels staged per barrier (BK = 32*NP)
// <4,4,1>: 128x128 tile, BK=32, 48 MFMAs/barrier-pair, 32 KB LDS (chunk gemms)
// <2,2,2>: 64x64 tile,  BK=64, 24 MFMAs/barrier-pair, 32 KB LDS (final gemm)
// XCD-aware 1D grid swizzle (b&7 = XCD stripe; each A-row-stripe stays in
// one XCD's L2, reused across all column tiles — round-8 verified: FETCH
// 68.8 -> 35.8 MB).
// strideA/strideB decouple row stride from K extent. K % (32*NP) == 0.
// ROUND-6 LESSON: never stream an MFMA operand global->VGPR.
// ============================================================
template <int WM, int WN, int NP>
__global__ __launch_bounds__(256) void gemm_mfma(
    const short* __restrict__ Ahi, const short* __restrict__ Alo,
    const short* __restrict__ Bhi, const short* __restrict__ Blo,
    float* __restrict__ C, const float* __restrict__ bias1, const float* __restrict__ bias2,
    int M, int N, int K, int strideA, int strideB) {
  constexpr int BM = 32 * WM, BN = 32 * WN;
  __shared__ short lds[(BM + BN) * 32 * NP * 2];
  short* Ah_s = lds;                        // [NP][BM][32]
  short* Al_s = Ah_s + NP * BM * 32;
  short* Bh_s = Al_s + NP * BM * 32;        // [NP][BN][32]
  short* Bl_s = Bh_s + NP * BN * 32;

  const int R = M / BM, NT = N / BN;
  int b = blockIdx.x;
  int xcd = b & 7, q = b >> 3;
  int ct = q % NT, rg = q / NT;
  int r = rg * 8 + xcd;
  if (r >= R) return;

  const int tid = threadIdx.x;
  const int wave = tid >> 6, lane = tid & 63;
  const int wm = wave >> 1, wn = wave & 1;
  const int bm = r * BM, bn = ct * BN;

  const int rA = lane >> 2;          // 0..15
  const int cA = (lane & 3) * 8;     // 16B unit within 32-k panel row

  f32x4 acc[WM][WN];
  #pragma unroll
  for (int tm = 0; tm < WM; ++tm)
    #pragma unroll
    for (int tn = 0; tn < WN; ++tn) acc[tm][tn] = {0.f, 0.f, 0.f, 0.f};

  for (int k0 = 0; k0 < K; k0 += 32 * NP) {
    #pragma unroll
    for (int p = 0; p < NP; ++p) {
      int kk = k0 + p * 32;
      #pragma unroll
      for (int i = 0; i < BM / 64; ++i) {
        int row = i * 64 + wave * 16;
        size_t go = (size_t)(bm + row + rA) * strideA + kk + cA;
        int lo = p * BM * 32 + row * 32;
        gl2lds16(Ahi + go, Ah_s + lo);
        gl2lds16(Alo + go, Al_s + lo);
      }
      #pragma unroll
      for (int i = 0; i < BN / 64; ++i) {
        int row = i * 64 + wave * 16;
        size_t go = (size_t)(bn + row + rA) * strideB + kk + cA;
        int lo = p * BN * 32 + row * 32;
        gl2lds16(Bhi + go, Bh_s + lo);
        gl2lds16(Blo + go, Bl_s + lo);
      }
    }
    __syncthreads();

    const int fr = lane & 15;
    const int fk = (lane >> 4) * 8;
    #pragma unroll
    for (int p = 0; p < NP; ++p) {
      const int pA = p * BM * 32, pB = p * BN * 32;
      bf16x8 a_h[WM], a_l[WM], b_h[WN], b_l[WN];
      #pragma unroll
      for (int tm = 0; tm < WM; ++tm) {
        int rr = (wm * WM + tm) * 16 + fr;
        a_h[tm] = *(const bf16x8*)(Ah_s + pA + rr * 32 + fk);
        a_l[tm] = *(const bf16x8*)(Al_s + pA + rr * 32 + fk);
      }
      #pragma unroll
      for (int tn = 0; tn < WN; ++tn) {
        int rr = (wn * WN + tn) * 16 + fr;
        b_h[tn] = *(const bf16x8*)(Bh_s + pB + rr * 32 + fk);
        b_l[tn] = *(const bf16x8*)(Bl_s + pB + rr * 32 + fk);
      }
      #pragma unroll
      for (int tm = 0; tm < WM; ++tm)
        #pragma unroll
        for (int tn = 0; tn < WN; ++tn) {
          acc[tm][tn] = __builtin_amdgcn_mfma_f32_16x16x32_bf16(a_h[tm], b_h[tn], acc[tm][tn], 0, 0, 0);
          acc[tm][tn] = __builtin_amdgcn_mfma_f32_16x16x32_bf16(a_h[tm], b_l[tn], acc[tm][tn], 0, 0, 0);
          acc[tm][tn] = __builtin_amdgcn_mfma_f32_16x16x32_bf16(a_l[tm], b_h[tn], acc[tm][tn], 0, 0, 0);
        }
    }
    __syncthreads();
  }

  // epilogue: C/D layout col=lane&15, row=(lane>>4)*4+reg  [m89/m91 verified]
  const int col0 = lane & 15, rq = (lane >> 4) * 4;
  #pragma unroll
  for (int tm = 0; tm < WM; ++tm)
    #pragma unroll
    for (int tn = 0; tn < WN; ++tn) {
      int col = bn + (wn * WN + tn) * 16 + col0;
      float badd = 0.f;
      if (bias1) badd += bias1[col];
      if (bias2) badd += bias2[col];
      #pragma unroll
      for (int rr = 0; rr < 4; ++rr) {
        int row = bm + (wm * WM + tm) * 16 + rq + rr;
        C[(size_t)row * N + col] = acc[tm][tn][rr] + badd;
      }
    }
}

// ============================================================
// GAT layer 2 (round-4 version — verified)
// ============================================================
__global__ __launch_bounds__(256) void gat2_kernel(
    const float* __restrict__ xlr, const int* __restrict__ src, const int* __restrict__ dst,
    const float* __restrict__ ea, const float* __restrict__ We,
    const float* __restrict__ att, const float* __restrict__ bias,
    short* __restrict__ h2hi, short* __restrict__ h2lo, int g0) {
  __shared__ float xl_s[512 * N_NODES];   // [j][s]
  __shared__ float xr_s[512 * N_NODES];   // [j][d]
  __shared__ alignas(16) float We_s[3 * 512];
  __shared__ alignas(16) float att_s[512];
  __shared__ float b_s[HID];
  __shared__ float easX[EPG], easY[EPG], easZ[EPG];
  __shared__ float logit_s[HEADS * 65];
  __shared__ int sloc[EPG], dloc[EPG], deg[N_NODES], start[N_NODES], fill[N_NODES], elist[EPG];

  const int g = g0 + blockIdx.x, tid = threadIdx.x;
  const int nb = g * N_NODES, eb = g * EPG;
  const int lb = blockIdx.x * N_NODES;

  for (int i = tid; i < 1536; i += 256) We_s[i] = We[i];
  for (int i = tid; i < 512; i += 256) att_s[i] = att[i];
  if (tid < HID) b_s[tid] = bias[tid];
  for (int i = tid; i < N_NODES * 1024; i += 256) {
    int s = i >> 10, j = i & 1023;
    float v = xlr[(size_t)(lb + s) * 1024 + j];
    if (j < 512) xl_s[j * N_NODES + s] = v;
    else         xr_s[(j - 512) * N_NODES + s] = v;
  }
  if (tid < EPG) {
    easX[tid] = ea[(eb + tid) * 3 + 0];
    easY[tid] = ea[(eb + tid) * 3 + 1];
    easZ[tid] = ea[(eb + tid) * 3 + 2];
    sloc[tid] = src[eb + tid] - nb;
    dloc[tid] = dst[eb + tid] - nb;
  }
  if (tid < N_NODES) { deg[tid] = 0; fill[tid] = 0; }
  __syncthreads();
  if (tid < EPG) atomicAdd(&deg[dloc[tid]], 1);
  __syncthreads();
  if (tid == 0) { int a = 0; for (int n = 0; n < N_NODES; ++n) { start[n] = a; a += deg[n]; } }
  __syncthreads();
  if (tid < EPG) { int d = dloc[tid]; int p = atomicAdd(&fill[d], 1); elist[start[d] + p] = tid; }

  for (int t = tid; t < EPG * HEADS; t += 256) {
    int h = t >> 6, e = t & 63;
    int s = sloc[e], d = dloc[e];
    float e0 = easX[e], e1 = easY[e], e2 = easZ[e];
    float acc = 0.f;
    int base = h * 64;
    #pragma unroll
    for (int c4 = 0; c4 < 16; ++c4) {
      int j = base + c4 * 4;
      f32x4 we0 = *(const f32x4*)(We_s + j);
      f32x4 we1 = *(const f32x4*)(We_s + 512 + j);
      f32x4 we2 = *(const f32x4*)(We_s + 1024 + j);
      f32x4 at  = *(const f32x4*)(att_s + j);
      #pragma unroll
      for (int q = 0; q < 4; ++q) {
        int jj = j + q;
        float v = xl_s[jj * N_NODES + s] + xr_s[jj * N_NODES + d]
                + e0 * we0[q] + e1 * we1[q] + e2 * we2[q];
        acc += lreluf_(v) * at[q];
      }
    }
    logit_s[h * 65 + e] = acc;
  }
  __syncthreads();

  for (int t = tid; t < HEADS * 64; t += 256) {
    int h = t >> 6, n = t & 63;
    if (n < N_NODES) {
      int s0 = start[n], dn = deg[n];
      float mx = -1e30f;
      for (int i = 0; i < dn; ++i) mx = fmaxf(mx, logit_s[h * 65 + elist[s0 + i]]);
      float den = 0.f;
      for (int i = 0; i < dn; ++i) den += expf(logit_s[h * 65 + elist[s0 + i]] - mx);
      float inv = 1.f / (den + 1e-16f);
      for (int i = 0; i < dn; ++i) {
        int e = elist[s0 + i];
        logit_s[h * 65 + e] = expf(logit_s[h * 65 + e] - mx) * inv;
      }
    }
  }
  __syncthreads();

  for (int t = tid; t < N_NODES * 8; t += 256) {
    int n = t >> 3, jb = t & 7;
    int j0 = jb * 8;
    float acc[8] = {};
    int s0 = start[n], dn = deg[n];
    for (int i = 0; i < dn; ++i) {
      int e = elist[s0 + i]; int s = sloc[e];
      float al[8];
      #pragma unroll
      for (int h = 0; h < 8; ++h) al[h] = logit_s[h * 65 + e];
      #pragma unroll
      for (int cc = 0; cc < 8; ++cc) {
        int c = j0 + cc;
        float sum = 0.f;
        #pragma unroll
        for (int h = 0; h < 8; ++h) sum += al[h] * xl_s[(h * 64 + c) * N_NODES + s];
        acc[cc] += sum;
      }
    }
    bf16x8 vh, vl;
    #pragma unroll
    for (int cc = 0; cc < 8; ++cc) {
      float v = eluf_(acc[cc] * 0.125f + b_s[j0 + cc]);
      short hb = f2bf(v);
      vh[cc] = hb;
      vl[cc] = f2bf(v - bf2f(hb));
    }
    size_t o = (size_t)(nb + n) * HID + j0;
    *(bf16x8*)(h2hi + o) = vh;
    *(bf16x8*)(h2lo + o) = vl;
  }
}

// ============================================================
// LSTM1 (round-5 no-spill version) + rest of the chain
// ============================================================
__global__ __launch_bounds__(1024, 4) void lstm1_kernel(
    const float* __restrict__ X, const float* __restrict__ Whh, float* __restrict__ Y) {
  __shared__ float hs[LSTM1_H], cs[LSTM1_H], part[4 * LSTM1_H], gs[4 * LSTM1_H];
  const int tid = threadIdx.x;
  const int j = tid & 511, half = tid >> 9;
  const int b = blockIdx.x;
  float4 w[16];
  const float4* wp = (const float4*)(Whh + (size_t)j * LSTM1_H + half * 64);
  #pragma unroll
  for (int q = 0; q < 16; ++q) w[q] = wp[q];
  if (tid < LSTM1_H) { hs[tid] = 0.f; cs[tid] = 0.f; }
  __syncthreads();
  for (int t = 0; t < SEQ; ++t) {
    const float* hb = hs + half * 64;
    float acc = 0.f;
    #pragma unroll
    for (int q = 0; q < 16; ++q) {
      acc += w[q].x * hb[4 * q] + w[q].y * hb[4 * q + 1]
           + w[q].z * hb[4 * q + 2] + w[q].w * hb[4 * q + 3];
    }
    if (half) part[j] = acc;
    __syncthreads();
    if (!half) gs[j] = acc + part[j] + X[((size_t)b * SEQ + t) * 512 + j];
    __syncthreads();
    if (tid < LSTM1_H) {
      float ig = sigmoidf_(gs[tid]);
      float fg = sigmoidf_(gs[LSTM1_H + tid]);
      float gg = tanhf(gs[2 * LSTM1_H + tid]);
      float og = sigmoidf_(gs[3 * LSTM1_H + tid]);
      float c = fg * cs[tid] + ig * gg;
      cs[tid] = c;
      float h = og * tanhf(c);
      hs[tid] = h;
      Y[((size_t)b * SEQ + t) * LSTM1_H + tid] = h;
    }
    __syncthreads();
  }
}

__global__ __launch_bounds__(256) void x2_kernel(
    const float* __restrict__ Y1, const float* __restrict__ Wih,
    const float* __restrict__ bih, const float* __restrict__ bhh,
    float* __restrict__ X2) {
  __shared__ float ys[LSTM1_H];
  const int g = blockIdx.x, j = threadIdx.x;
  if (j < LSTM1_H) ys[j] = Y1[(size_t)g * LSTM1_H + j];
  __syncthreads();
  const float4* wp = (const float4*)(Wih + (size_t)j * LSTM1_H);
  float acc = bih[j] + bhh[j];
  #pragma unroll
  for (int q = 0; q < 32; ++q) {
    float4 w = wp[q];
    acc += w.x * ys[4 * q] + w.y * ys[4 * q + 1] + w.z * ys[4 * q + 2] + w.w * ys[4 * q + 3];
  }
  X2[(size_t)g * 256 + j] = acc;
}

__global__ __launch_bounds__(256, 2) void lstm2_fc_kernel(
    const float* __restrict__ X, const float* __restrict__ Whh,
    const float* __restrict__ fcW, const float* __restrict__ fcb,
    float* __restrict__ out) {
  __shared__ float hs[LSTM2_H], cs[LSTM2_H], gs[4 * LSTM2_H];
  const int b = blockIdx.x, j = threadIdx.x;
  float4 w[16];
  const float4* wp = (const float4*)(Whh + (size_t)j * LSTM2_H);
  #pragma unroll
  for (int q = 0; q < 16; ++q) w[q] = wp[q];
  if (j < LSTM2_H) { hs[j] = 0.f; cs[j] = 0.f; }
  __syncthreads();
  for (int t = 0; t < SEQ; ++t) {
    float acc = X[((size_t)b * SEQ + t) * 256 + j];
    #pragma unroll
    for (int q = 0; q < 16; ++q) {
      acc += w[q].x * hs[4 * q] + w[q].y * hs[4 * q + 1]
           + w[q].z * hs[4 * q + 2] + w[q].w * hs[4 * q + 3];
    }
    gs[j] = acc;
    __syncthreads();
    if (j < LSTM2_H) {
      float ig = sigmoidf_(gs[j]);
      float fg = sigmoidf_(gs[LSTM2_H + j]);
      float gg = tanhf(gs[2 * LSTM2_H + j]);
      float og = sigmoidf_(gs[3 * LSTM2_H + j]);
      float c = fg * cs[j] + ig * gg;
      cs[j] = c;
      hs[j] = og * tanhf(c);
    }
    __syncthreads();
  }
  if (j < 4) {
    float acc = fcb[j];
    #pragma unroll
    for (int k = 0; k < LSTM2_H; ++k) acc += fcW[j * LSTM2_H + k] * hs[k];
    out[b * 4 + j] = acc;
  }
}

// ============================================================
extern "C" void kernel_launch(void* const* d_in, const int* in_sizes, int n_in,
                              void* d_out, int out_size, void* d_ws, size_t ws_size,
                              hipStream_t stream) {
  const float* x       = (const float*)d_in[0];
  const int*   eidx    = (const int*)d_in[1];
  const float* eattr   = (const float*)d_in[2];
  const float* g1_Wl   = (const float*)d_in[3];
  const float* g1_Wr   = (const float*)d_in[4];
  const float* g1_We   = (const float*)d_in[5];
  const float* g1_att  = (const float*)d_in[6];
  const float* g1_b    = (const float*)d_in[7];
  const float* g2_Wl   = (const float*)d_in[8];
  const float* g2_Wr   = (const float*)d_in[9];
  const float* g2_We   = (const float*)d_in[10];
  const float* g2_att  = (const float*)d_in[11];
  const float* g2_b    = (const float*)d_in[12];
  const float* l1_Wih  = (const float*)d_in[13];
  const float* l1_Whh  = (const float*)d_in[14];
  const float* l1_bih  = (const float*)d_in[15];
  const float* l1_bhh  = (const float*)d_in[16];
  const float* l2_Wih  = (const float*)d_in[17];
  const float* l2_Whh  = (const float*)d_in[18];
  const float* l2_bih  = (const float*)d_in[19];
  const float* l2_bhh  = (const float*)d_in[20];
  const float* fc_W    = (const float*)d_in[21];
  const float* fc_b    = (const float*)d_in[22];
  float* out = (float*)d_out;

  const int* src = eidx;
  const int* dst = eidx + E_EDGES;

  // ---- runtime-adaptive chunking: largest chunk size whose ws layout fits.
  // ws_size is constant across calls -> same branch every call (graph-safe).
  const int cand[5] = {1, 2, 3, 4, 6};
  int nchunks = 0;
  short *h1hi = nullptr, *h1lo = nullptr, *h2hi = nullptr, *h2lo = nullptr;
  short *B2hi = nullptr, *B2lo = nullptr, *W1hi = nullptr, *W1lo = nullptr;
  float *xlr2c = nullptr, *X1 = nullptr, *Y1 = nullptr, *X2 = nullptr;
  int chunk_g = 0, chunk_n = 0;
  for (int ci = 0; ci < 5; ++ci) {
    int C = cand[ci];
    int CG = G_GRAPHS / C, CN = CG * N_NODES;
    char* p = (char*)d_ws;
    auto alloc = [&](size_t bytes) { char* r = p; p += (bytes + 255) & ~(size_t)255; return r; };
    short* t_h1hi  = (short*)alloc((size_t)CN * HC * 2);
    short* t_h1lo  = (short*)alloc((size_t)CN * HC * 2);
    float* t_xlr2c = (float*)alloc((size_t)CN * 1024 * 4);
    short* t_h2hi  = (short*)alloc((size_t)G_GRAPHS * 2112 * 2);
    short* t_h2lo  = (short*)alloc((size_t)G_GRAPHS * 2112 * 2);
    short* t_B2hi  = (short*)alloc((size_t)1024 * 512 * 2);
    short* t_B2lo  = (short*)alloc((size_t)1024 * 512 * 2);
    short* t_W1hi  = (short*)alloc((size_t)512 * 2112 * 2);
    short* t_W1lo  = (short*)alloc((size_t)512 * 2112 * 2);
    float* t_X1    = (float*)alloc((size_t)G_GRAPHS * 512 * 4);
    float* t_Y1    = (float*)alloc((size_t)G_GRAPHS * LSTM1_H * 4);
    float* t_X2    = (float*)alloc((size_t)G_GRAPHS * 256 * 4);
    if ((size_t)(p - (char*)d_ws) <= ws_size) {
      nchunks = C; chunk_g = CG; chunk_n = CN;
      h1hi = t_h1hi; h1lo = t_h1lo; xlr2c = t_xlr2c;
      h2hi = t_h2hi; h2lo = t_h2lo; B2hi = t_B2hi; B2lo = t_B2lo;
      W1hi = t_W1hi; W1lo = t_W1lo; X1 = t_X1; Y1 = t_Y1; X2 = t_X2;
      break;
    }
  }
  if (nchunks == 0) return;   // guard: zero output instead of memory fault

  conv_all<<<2048 + (512 * 2112 + 255) / 256, 256, 0, stream>>>(
      g2_Wl, g2_Wr, B2hi, B2lo, l1_Wih, W1hi, W1lo);

  for (int c = 0; c < nchunks; ++c) {
    int g0 = c * chunk_g;
    gat1_kernel<<<chunk_g, 256, 0, stream>>>(x, src, dst, eattr, g1_Wl, g1_Wr, g1_We,
                                             g1_att, g1_b, h1hi, h1lo, g0);
    // 128x128 tiles, BK=32, XCD-swizzled 1D grid
    int R = chunk_n / 128, NT = 1024 / 128;
    int gblocks = 8 * ((R + 7) / 8) * NT;
    gemm_mfma<4, 4, 1><<<gblocks, 256, 0, stream>>>(h1hi, h1lo, B2hi, B2lo, xlr2c,
                                                    (const float*)nullptr, (const float*)nullptr,
                                                    chunk_n, 1024, HC, HC, HC);
    gat2_kernel<<<chunk_g, 256, 0, stream>>>(xlr2c, src, dst, eattr, g2_We,
                                             g2_att, g2_b, h2hi, h2lo, g0);
  }

  // X1 = h2 @ l1_Wih^T + biases  (single dispatch, 64x64 tiles, BK=64: 192 blocks)
  {
    int R = G_GRAPHS / 64, NT = 512 / 64;
    int gblocks = 8 * ((R + 7) / 8) * NT;
    gemm_mfma<2, 2, 2><<<gblocks, 256, 0, stream>>>(h2hi, h2lo, W1hi, W1lo, X1,
                                                    l1_bih, l1_bhh,
                                                    G_GRAPHS, 512, N_NODES * HID,
                                                    N_NODES * HID, N_NODES * HID);
  }

  lstm1_kernel<<<BATCH, 1024, 0, stream>>>(X1, l1_Whh, Y1);
  x2_kernel<<<G_GRAPHS, 256, 0, stream>>>(Y1, l2_Wih, l2_bih, l2_bhh, X2);
  lstm2_fc_kernel<<<BATCH, 256, 0, stream>>>(X2, l2_Whh, fc_W, fc_b, out);
}